// Round 4
// baseline (434.239 us; speedup 1.0000x reference)
//
#include <hip/hip_runtime.h>

#define S_LEN 2048
#define BATCH 2
#define NH 32
#define NKV 8
#define HD 64
#define HID 2048
#define NTOK (BATCH * S_LEN)   // 4096

typedef __attribute__((ext_vector_type(8))) __bf16 bf16x8;
typedef __attribute__((ext_vector_type(4))) float f32x4;

__device__ inline ushort f2b(float f) {
    union { float f; unsigned u; } x{f};
    unsigned r = (x.u + 0x7fff + ((x.u >> 16) & 1)) >> 16;
    return (ushort)r;
}
__device__ inline float b2f(ushort u) {
    union { unsigned u; float f; } x{(unsigned)u << 16};
    return x.f;
}

// ---------------- fp32 -> bf16 conversion ----------------
__global__ __launch_bounds__(256) void cvt_f32_bf16(const float* __restrict__ in,
                                                    ushort* __restrict__ out, int n4) {
    int i = blockIdx.x * 256 + threadIdx.x;
    if (i >= n4) return;
    float4 v = reinterpret_cast<const float4*>(in)[i];
    ushort4 o;
    o.x = f2b(v.x); o.y = f2b(v.y); o.z = f2b(v.z); o.w = f2b(v.w);
    reinterpret_cast<ushort4*>(out)[i] = o;
}

// ---------------- global -> LDS async helper ----------------
__device__ inline void gl_lds16(const void* g, void* l) {
    __builtin_amdgcn_global_load_lds((const __attribute__((address_space(1))) void*)g,
                                     (__attribute__((address_space(3))) void*)l, 16, 0, 0);
}

// ---------------- GEMM: C[m][n] = sum_k A[m][k] * B[n][k] ----------------
template<int WF32>
__global__ __launch_bounds__(256) void gemm_bt(const ushort* __restrict__ A,
                                               const ushort* __restrict__ B,
                                               void* __restrict__ C,
                                               int M, int N, int K) {
    __shared__ __align__(16) ushort As[128 * 32];
    __shared__ __align__(16) ushort Bs[128 * 32];
    const int tid = threadIdx.x, lane = tid & 63, w = tid >> 6;
    const int wr = w >> 1, wc = w & 1, l15 = lane & 15, lg = lane >> 4;
    const int m0 = blockIdx.y * 128, n0 = blockIdx.x * 128;

    const ushort* Ag = A + (size_t)(m0 + (tid >> 2)) * K + (tid & 3) * 8;
    const ushort* Bg = B + (size_t)(n0 + (tid >> 2)) * K + (tid & 3) * 8;
    ushort* lA = As + w * 512;
    ushort* lB = Bs + w * 512;

    f32x4 acc[4][4] = {};

    for (int k0 = 0; k0 < K; k0 += 32) {
        __syncthreads();
        gl_lds16(Ag + k0, lA);
        gl_lds16(Ag + (size_t)64 * K + k0, lA + 2048);
        gl_lds16(Bg + k0, lB);
        gl_lds16(Bg + (size_t)64 * K + k0, lB + 2048);
        __syncthreads();

        const ushort* pa = As + (wr * 64 + l15) * 32 + lg * 8;
        const ushort* pb = Bs + (wc * 64 + l15) * 32 + lg * 8;
        bf16x8 af[4], bff[4];
#pragma unroll
        for (int i = 0; i < 4; i++) {
            af[i]  = *(const bf16x8*)(pa + i * 512);
            bff[i] = *(const bf16x8*)(pb + i * 512);
        }
#pragma unroll
        for (int i = 0; i < 4; i++)
#pragma unroll
            for (int j = 0; j < 4; j++)
                acc[i][j] = __builtin_amdgcn_mfma_f32_16x16x32_bf16(af[i], bff[j], acc[i][j], 0, 0, 0);
    }

    const int mr = m0 + wr * 64 + lg * 4, nc = n0 + wc * 64 + l15;
#pragma unroll
    for (int i = 0; i < 4; i++)
#pragma unroll
        for (int j = 0; j < 4; j++)
#pragma unroll
            for (int r = 0; r < 4; r++) {
                size_t row = mr + i * 16 + r, col = nc + j * 16;
                if (WF32) ((float*)C)[row * N + col] = acc[i][j][r];
                else      ((ushort*)C)[row * N + col] = f2b(acc[i][j][r]);
            }
}

// ---------------- RoPE (in place, bf16) ----------------
__global__ __launch_bounds__(256) void rope_k(ushort* __restrict__ X, int nheads, int stride, int total) {
    int idx = blockIdx.x * 256 + threadIdx.x;
    int np = nheads * 32;
    if (idx >= total) return;
    int t = idx / np, p = idx - t * np;
    int hh = p >> 5, i = p & 31;
    int pos = t & (S_LEN - 1);
    float ang = (float)pos * exp2f(-(float)i * 0.4152410118609203f);
    float sv, cv;
    sincosf(ang, &sv, &cv);
    ushort* base = X + (size_t)t * stride + hh * 64 + i;
    float x1 = b2f(base[0]), x2 = b2f(base[32]);
    base[0]  = f2b(x1 * cv - x2 * sv);
    base[32] = f2b(x2 * cv + x1 * sv);
}

// ---------------- V transpose: from KV buffer (stride 1024, V at +512) ----------------
__global__ __launch_bounds__(256) void transpose_v(const ushort* __restrict__ KV,
                                                   ushort* __restrict__ Vt) {
    __shared__ ushort tile[32][33];
    int bz = blockIdx.z, b = bz >> 3, kvh = bz & 7;
    int s0 = blockIdx.x * 32, d0 = blockIdx.y * 32;
    int tx = threadIdx.x & 31, ty = threadIdx.x >> 5;
#pragma unroll
    for (int i = 0; i < 4; i++)
        tile[ty + i * 8][tx] = KV[(size_t)(b * S_LEN + s0 + ty + i * 8) * 1024 + 512 + kvh * 64 + d0 + tx];
    __syncthreads();
#pragma unroll
    for (int i = 0; i < 4; i++)
        Vt[((size_t)((b * 8 + kvh) * 64 + d0 + ty + i * 8)) * S_LEN + s0 + tx] = tile[tx][ty + i * 8];
}

// ---------------- Flash attention (causal, GQA) ----------------
// Two q-tiles per wave (q0, q0+64) sharing one set of K/V registers:
// halves scattered K/V loads and doubles per-wave ILP (two independent
// softmax chains). Swapped QK^T + permuted K rows (P born in A-frag order).
__global__ __launch_bounds__(256, 3) void attn_k(const ushort* __restrict__ Q,
                                                 const ushort* __restrict__ Kc,   // KV buffer, stride 1024
                                                 const ushort* __restrict__ Vt,
                                                 ushort* __restrict__ O) {
    const int lane = threadIdx.x & 63, w = threadIdx.x >> 6;
    const int l15 = lane & 15, lg = lane >> 4;
    const int bh = blockIdx.y, b = bh >> 5, h = bh & 31, kvh = h >> 2;
    const int KROW = 1024;
    const int Bq = blockIdx.x;

    const ushort* KbaseH = Kc + (size_t)(b * S_LEN) * KROW + kvh * 64 + lg * 8;
    const ushort* Vb = Vt + ((size_t)((b * 8 + kvh) * 64 + l15)) * S_LEN + lg * 8;

    // permuted kv-row offset: output reg (kc,r) at lane-group lg holds
    // kv = 32*(kc>>1) + 8*lg + 4*(kc&1) + r
    int kvoff[4];
#pragma unroll
    for (int kc = 0; kc < 4; kc++)
        kvoff[kc] = ((kc >> 1) << 5) + ((l15 >> 2) << 3) + ((kc & 1) << 2) + (l15 & 3);

    const int q0A = Bq * 128 + w * 16, q0B = q0A + 64;
    const int qrowA = q0A + l15, qrowB = q0B + l15;
    const int ktA = Bq * 2, ktB = ktA + 1;

    const ushort* qap = Q + (size_t)(b * S_LEN + qrowA) * HID + h * 64 + lg * 8;
    const ushort* qbp = Q + (size_t)(b * S_LEN + qrowB) * HID + h * 64 + lg * 8;
    bf16x8 qfA0 = *(const bf16x8*)qap, qfA1 = *(const bf16x8*)(qap + 32);
    bf16x8 qfB0 = *(const bf16x8*)qbp, qfB1 = *(const bf16x8*)(qbp + 32);

    f32x4 aoA[4] = {}, aoB[4] = {};
    float mA = -INFINITY, lAcc = 0.f, mB = -INFINITY, lBcc = 0.f;

    bf16x8 kf[4][2], vf[4][2];
    auto load_k = [&](int kn) {
#pragma unroll
        for (int kc = 0; kc < 4; kc++) {
            const ushort* kp = KbaseH + (size_t)(kn + kvoff[kc]) * KROW;
            kf[kc][0] = *(const bf16x8*)kp;
            kf[kc][1] = *(const bf16x8*)(kp + 32);
        }
    };
    auto load_v = [&](int kn) {
#pragma unroll
        for (int dt = 0; dt < 4; dt++) {
            const ushort* vp = Vb + (size_t)dt * 16 * S_LEN + kn;
            vf[dt][0] = *(const bf16x8*)vp;
            vf[dt][1] = *(const bf16x8*)(vp + 32);
        }
    };

    auto qkt = [&](bf16x8 q0f, bf16x8 q1f, f32x4* s) {
#pragma unroll
        for (int kc = 0; kc < 4; kc++) {
            f32x4 z = {};
            z = __builtin_amdgcn_mfma_f32_16x16x32_bf16(kf[kc][0], q0f, z, 0, 0, 0);
            z = __builtin_amdgcn_mfma_f32_16x16x32_bf16(kf[kc][1], q1f, z, 0, 0, 0);
            s[kc] = z;
        }
    };
    auto mask_diag = [&](f32x4* s, int kn, int qrow) {
#pragma unroll
        for (int kc = 0; kc < 4; kc++)
#pragma unroll
            for (int r = 0; r < 4; r++) {
                int kv = kn + ((kc >> 1) << 5) + (lg << 3) + ((kc & 1) << 2) + r;
                s[kc][r] = (kv <= qrow) ? s[kc][r] : -INFINITY;
            }
    };
    // softmax + PV for one tile (scale 0.125 folded via natural exp)
    auto smax_pv = [&](f32x4* s, float& m, float& lacc, f32x4* ao) {
        float pm = s[0][0];
#pragma unroll
        for (int kc = 0; kc < 4; kc++)
#pragma unroll
            for (int r = 0; r < 4; r++) pm = fmaxf(pm, s[kc][r]);
        pm = fmaxf(pm, __shfl_xor(pm, 16, 64));
        pm = fmaxf(pm, __shfl_xor(pm, 32, 64));
        if (!__all(pm <= m)) {
            float mn = fmaxf(m, pm);
            float sc = __expf((m - mn) * 0.125f);   // first tile: __expf(-inf)=0
            m = mn;
            lacc *= sc;
            float scr[4];
#pragma unroll
            for (int r = 0; r < 4; r++) scr[r] = __shfl(sc, (lg << 2) + r, 64);
#pragma unroll
            for (int dt = 0; dt < 4; dt++)
#pragma unroll
                for (int r = 0; r < 4; r++) ao[dt][r] *= scr[r];
        }
        const float nb = -m * 0.125f;
        float ps = 0.f;
        bf16x8 pf0, pf1;
#pragma unroll
        for (int r = 0; r < 4; r++) {
            float p0 = __expf(fmaf(s[0][r], 0.125f, nb));
            float p1 = __expf(fmaf(s[1][r], 0.125f, nb));
            float p2 = __expf(fmaf(s[2][r], 0.125f, nb));
            float p3 = __expf(fmaf(s[3][r], 0.125f, nb));
            ps += (p0 + p1) + (p2 + p3);
            pf0[r]     = (__bf16)p0;
            pf0[4 + r] = (__bf16)p1;
            pf1[r]     = (__bf16)p2;
            pf1[4 + r] = (__bf16)p3;
        }
        lacc += ps;
#pragma unroll
        for (int dt = 0; dt < 4; dt++) {
            ao[dt] = __builtin_amdgcn_mfma_f32_16x16x32_bf16(pf0, vf[dt][0], ao[dt], 0, 0, 0);
            ao[dt] = __builtin_amdgcn_mfma_f32_16x16x32_bf16(pf1, vf[dt][1], ao[dt], 0, 0, 0);
        }
    };

    load_k(0);
    load_v(0);

    // shared iterations: both q-tiles consume the same K/V tile
    for (int kt = 0; kt <= ktA; ++kt) {
        const int kn = kt << 6;
        f32x4 sA[4], sB[4];
        qkt(qfA0, qfA1, sA);
        qkt(qfB0, qfB1, sB);
        load_k(kn + 64);                       // always valid: kt+1 <= ktB
        if (kt == ktA) mask_diag(sA, kn, qrowA);
        smax_pv(sA, mA, lAcc, aoA);
        smax_pv(sB, mB, lBcc, aoB);
        if (kt < ktA) load_v(kn + 64);
        else          load_v(ktB << 6);
    }
    // final tile: B only (diagonal)
    {
        const int kn = ktB << 6;
        f32x4 sB[4];
        qkt(qfB0, qfB1, sB);
        mask_diag(sB, kn, qrowB);
        smax_pv(sB, mB, lBcc, aoB);
    }

    auto epi = [&](f32x4* ao, float lacc, int q0) {
        lacc += __shfl_xor(lacc, 16, 64);
        lacc += __shfl_xor(lacc, 32, 64);
        float inv = 1.0f / lacc;
        float invr[4];
#pragma unroll
        for (int r = 0; r < 4; r++) invr[r] = __shfl(inv, (lg << 2) + r, 64);
        ushort* ob = O + (size_t)(b * S_LEN + q0 + lg * 4) * HID + h * 64 + l15;
#pragma unroll
        for (int dt = 0; dt < 4; dt++)
#pragma unroll
            for (int r = 0; r < 4; r++)
                ob[(size_t)r * HID + dt * 16] = f2b(ao[dt][r] * invr[r]);
    };
    epi(aoA, lAcc, q0A);
    epi(aoB, lBcc, q0B);
}

// ---------------- launch ----------------
extern "C" void kernel_launch(void* const* d_in, const int* in_sizes, int n_in,
                              void* d_out, int out_size, void* d_ws, size_t ws_size,
                              hipStream_t stream) {
    const float* hidden = (const float*)d_in[0];
    const float* Wq = (const float*)d_in[1];
    const float* Wk = (const float*)d_in[2];
    const float* Wv = (const float*)d_in[3];
    const float* Wo = (const float*)d_in[4];

    char* ws = (char*)d_ws;
    size_t off = 0;
    auto alloc = [&](size_t bytes) -> void* {
        void* p = ws + off;
        off += (bytes + 255) & ~(size_t)255;
        return p;
    };
    ushort* hb  = (ushort*)alloc((size_t)NTOK * HID * 2);
    ushort* wq  = (ushort*)alloc((size_t)2048 * 2048 * 2);
    ushort* wkv = (ushort*)alloc((size_t)1024 * 2048 * 2);
    ushort* wo  = (ushort*)alloc((size_t)2048 * 2048 * 2);
    ushort* Qb  = (ushort*)alloc((size_t)NTOK * 2048 * 2);
    ushort* KVb = (ushort*)alloc((size_t)NTOK * 1024 * 2);
    ushort* Vtb = (ushort*)alloc((size_t)NTOK * 512 * 2);
    ushort* AO  = (ushort*)alloc((size_t)NTOK * 2048 * 2);

    auto cvt = [&](const float* in, ushort* out, int n) {
        int n4 = n / 4;
        cvt_f32_bf16<<<(n4 + 255) / 256, 256, 0, stream>>>(in, out, n4);
    };
    cvt(hidden, hb, NTOK * HID);
    cvt(Wq, wq, 2048 * 2048);
    cvt(Wk, wkv, 512 * 2048);
    cvt(Wv, wkv + (size_t)512 * 2048, 512 * 2048);
    cvt(Wo, wo, 2048 * 2048);

    gemm_bt<0><<<dim3(16, 32), 256, 0, stream>>>(hb, wq, Qb, NTOK, 2048, 2048);
    gemm_bt<0><<<dim3(8, 32), 256, 0, stream>>>(hb, wkv, KVb, NTOK, 1024, 2048);

    rope_k<<<(NTOK * NH * 32 + 255) / 256, 256, 0, stream>>>(Qb, NH, 2048, NTOK * NH * 32);
    rope_k<<<(NTOK * NKV * 32 + 255) / 256, 256, 0, stream>>>(KVb, NKV, 1024, NTOK * NKV * 32);
    transpose_v<<<dim3(S_LEN / 32, 2, BATCH * NKV), 256, 0, stream>>>(KVb, Vtb);

    attn_k<<<dim3(S_LEN / 128, BATCH * NH), 256, 0, stream>>>(Qb, KVb, Vtb, AO);

    gemm_bt<1><<<dim3(16, 32), 256, 0, stream>>>(AO, wo, d_out, NTOK, 2048, 2048);
}

// Round 6
// 267.946 us; speedup vs baseline: 1.6206x; 1.6206x over previous
//
#include <hip/hip_runtime.h>

#define S_LEN 2048
#define BATCH 2
#define NH 32
#define NKV 8
#define HD 64
#define HID 2048
#define NTOK (BATCH * S_LEN)   // 4096

typedef __attribute__((ext_vector_type(8))) __bf16 bf16x8;
typedef __attribute__((ext_vector_type(4))) float f32x4;

__device__ inline ushort f2b(float f) {
    union { float f; unsigned u; } x{f};
    unsigned r = (x.u + 0x7fff + ((x.u >> 16) & 1)) >> 16;
    return (ushort)r;
}
__device__ inline float b2f(ushort u) {
    union { unsigned u; float f; } x{(unsigned)u << 16};
    return x.f;
}

// ---------------- fp32 -> bf16 conversion ----------------
__global__ __launch_bounds__(256) void cvt_f32_bf16(const float* __restrict__ in,
                                                    ushort* __restrict__ out, int n4) {
    int i = blockIdx.x * 256 + threadIdx.x;
    if (i >= n4) return;
    float4 v = reinterpret_cast<const float4*>(in)[i];
    ushort4 o;
    o.x = f2b(v.x); o.y = f2b(v.y); o.z = f2b(v.z); o.w = f2b(v.w);
    reinterpret_cast<ushort4*>(out)[i] = o;
}

// ---------------- global -> LDS async helper ----------------
__device__ inline void gl_lds16(const void* g, void* l) {
    __builtin_amdgcn_global_load_lds((const __attribute__((address_space(1))) void*)g,
                                     (__attribute__((address_space(3))) void*)l, 16, 0, 0);
}

// ---------------- GEMM: C[m][n] = sum_k A[m][k] * B[n][k] ----------------
template<int WF32>
__global__ __launch_bounds__(256) void gemm_bt(const ushort* __restrict__ A,
                                               const ushort* __restrict__ B,
                                               void* __restrict__ C,
                                               int M, int N, int K) {
    __shared__ __align__(16) ushort As[128 * 32];
    __shared__ __align__(16) ushort Bs[128 * 32];
    const int tid = threadIdx.x, lane = tid & 63, w = tid >> 6;
    const int wr = w >> 1, wc = w & 1, l15 = lane & 15, lg = lane >> 4;
    const int m0 = blockIdx.y * 128, n0 = blockIdx.x * 128;

    const ushort* Ag = A + (size_t)(m0 + (tid >> 2)) * K + (tid & 3) * 8;
    const ushort* Bg = B + (size_t)(n0 + (tid >> 2)) * K + (tid & 3) * 8;
    ushort* lA = As + w * 512;
    ushort* lB = Bs + w * 512;

    f32x4 acc[4][4] = {};

    for (int k0 = 0; k0 < K; k0 += 32) {
        __syncthreads();
        gl_lds16(Ag + k0, lA);
        gl_lds16(Ag + (size_t)64 * K + k0, lA + 2048);
        gl_lds16(Bg + k0, lB);
        gl_lds16(Bg + (size_t)64 * K + k0, lB + 2048);
        __syncthreads();

        const ushort* pa = As + (wr * 64 + l15) * 32 + lg * 8;
        const ushort* pb = Bs + (wc * 64 + l15) * 32 + lg * 8;
        bf16x8 af[4], bff[4];
#pragma unroll
        for (int i = 0; i < 4; i++) {
            af[i]  = *(const bf16x8*)(pa + i * 512);
            bff[i] = *(const bf16x8*)(pb + i * 512);
        }
#pragma unroll
        for (int i = 0; i < 4; i++)
#pragma unroll
            for (int j = 0; j < 4; j++)
                acc[i][j] = __builtin_amdgcn_mfma_f32_16x16x32_bf16(af[i], bff[j], acc[i][j], 0, 0, 0);
    }

    const int mr = m0 + wr * 64 + lg * 4, nc = n0 + wc * 64 + l15;
#pragma unroll
    for (int i = 0; i < 4; i++)
#pragma unroll
        for (int j = 0; j < 4; j++)
#pragma unroll
            for (int r = 0; r < 4; r++) {
                size_t row = mr + i * 16 + r, col = nc + j * 16;
                if (WF32) ((float*)C)[row * N + col] = acc[i][j][r];
                else      ((ushort*)C)[row * N + col] = f2b(acc[i][j][r]);
            }
}

// ---------------- RoPE (in place, bf16) ----------------
__global__ __launch_bounds__(256) void rope_k(ushort* __restrict__ X, int nheads, int stride, int total) {
    int idx = blockIdx.x * 256 + threadIdx.x;
    int np = nheads * 32;
    if (idx >= total) return;
    int t = idx / np, p = idx - t * np;
    int hh = p >> 5, i = p & 31;
    int pos = t & (S_LEN - 1);
    float ang = (float)pos * exp2f(-(float)i * 0.4152410118609203f);
    float sv, cv;
    sincosf(ang, &sv, &cv);
    ushort* base = X + (size_t)t * stride + hh * 64 + i;
    float x1 = b2f(base[0]), x2 = b2f(base[32]);
    base[0]  = f2b(x1 * cv - x2 * sv);
    base[32] = f2b(x2 * cv + x1 * sv);
}

// ---------------- V transpose: from KV buffer (stride 1024, V at +512) ----------------
__global__ __launch_bounds__(256) void transpose_v(const ushort* __restrict__ KV,
                                                   ushort* __restrict__ Vt) {
    __shared__ ushort tile[32][33];
    int bz = blockIdx.z, b = bz >> 3, kvh = bz & 7;
    int s0 = blockIdx.x * 32, d0 = blockIdx.y * 32;
    int tx = threadIdx.x & 31, ty = threadIdx.x >> 5;
#pragma unroll
    for (int i = 0; i < 4; i++)
        tile[ty + i * 8][tx] = KV[(size_t)(b * S_LEN + s0 + ty + i * 8) * 1024 + 512 + kvh * 64 + d0 + tx];
    __syncthreads();
#pragma unroll
    for (int i = 0; i < 4; i++)
        Vt[((size_t)((b * 8 + kvh) * 64 + d0 + ty + i * 8)) * S_LEN + s0 + tx] = tile[tx][ty + i * 8];
}

// ---------------- Flash attention (causal, GQA) ----------------
// Block = 4 waves = 64 q rows, one (b,h). K/V tiles (64 kv) staged in LDS
// (double-buffered, 2-phase) via global_load_lds with pre-swizzled source;
// XOR swizzle f(row) on byte bits 4-6. Each staging op writes 1024 B at
// LDS base u*1024 B (u = w*2+j).  [R5 bug: base was u*2048 B -> OOB]
// Swapped QK^T + permuted K rows (P born in A-frag order, no LDS for P).
__global__ __launch_bounds__(256) void attn_k(const ushort* __restrict__ Q,
                                              const ushort* __restrict__ Kc,   // KV buffer, stride 1024
                                              const ushort* __restrict__ Vt,
                                              ushort* __restrict__ O) {
    __shared__ __align__(16) ushort K_lds[2][4096];
    __shared__ __align__(16) ushort V_lds[2][4096];
    const int lane = threadIdx.x & 63, w = threadIdx.x >> 6;
    const int l15 = lane & 15, lg = lane >> 4;
    const int bh = blockIdx.y, b = bh >> 5, h = bh & 31, kvh = h >> 2;

    // ---- staging: per-lane pre-swizzled global sources ----
    // op u = w*2+j writes LDS bytes [u*1024, (u+1)*1024); lane l writes 16B at +l*16.
    // LDS row = u*8 + (l>>3) (128 B rows), phys byte in row po = (l&7)*16;
    // content stored at po must be logical byte (po ^ f(row)).
    const ushort* kSrc[2];
    const ushort* vSrc[2];
    int dstU[2];
#pragma unroll
    for (int j = 0; j < 2; j++) {
        int u = w * 2 + j;
        int row = u * 8 + (lane >> 3);
        int po = (lane & 7) * 16;
        int fr = ((row & 3) | (((row >> 3) & 1) << 2)) << 4;
        int dus = (po ^ fr) >> 1;   // ushort offset within the 64-elem row
        kSrc[j] = Kc + (size_t)(b * S_LEN + row) * 1024 + kvh * 64 + dus;
        vSrc[j] = Vt + ((size_t)((b * 8 + kvh) * 64 + row)) * S_LEN + dus;
        dstU[j] = u * 512;          // ushort index: u*1024 bytes
    }

    // ---- fragment LDS byte offsets (2 bases each; kc/dt folded to immediates) ----
    // K frag row (perm): row = 32*(kc>>1) + 8*(l15>>2) + 4*(kc&1) + (l15&3)
    //   f(row) = ((l15&3) | ((l15>>2)&1)<<2) << 4  (independent of kc)
    int fr_k = ((l15 & 3) | (((l15 >> 2) & 1) << 2)) << 4;
    int kbase = 1024 * (l15 >> 2) + 128 * (l15 & 3) + ((lg * 16) ^ (fr_k & 48));
    int k6 = (fr_k >> 6) & 1;
    int kb0 = kbase + 64 * k6, kb1 = kbase + 64 * (1 - k6);
    // V frag row: row = dt*16 + l15; f(row) = ((l15&3) | ((l15>>3)&1)<<2) << 4
    int fr_v = ((l15 & 3) | (((l15 >> 3) & 1) << 2)) << 4;
    int vbase = 128 * l15 + ((lg * 16) ^ (fr_v & 48));
    int v6 = (fr_v >> 6) & 1;
    int vb0 = vbase + 64 * v6, vb1 = vbase + 64 * (1 - v6);

    for (int half = 0; half < 2; ++half) {
        const int bx = half ? (31 - blockIdx.x) : blockIdx.x;
        const int q0 = bx * 64 + w * 16;
        const int qrow = q0 + l15;
        const int ktend = bx;

        const ushort* qp = Q + (size_t)(b * S_LEN + qrow) * HID + h * 64 + lg * 8;
        bf16x8 qf0 = *(const bf16x8*)qp;
        bf16x8 qf1 = *(const bf16x8*)(qp + 32);

        f32x4 ao[4] = {};
        float m = -INFINITY, lacc = 0.f;

        // prologue: stage tile 0 into buf 0
#pragma unroll
        for (int j = 0; j < 2; j++) {
            gl_lds16(kSrc[j], &K_lds[0][dstU[j]]);
            gl_lds16(vSrc[j], &V_lds[0][dstU[j]]);
        }
        __syncthreads();
        int cur = 0;

        for (int kt = 0; kt <= ktend; ++kt) {
            const int kn = kt << 6;
            if (kt < ktend) {
                const int kn2 = kn + 64;
#pragma unroll
                for (int j = 0; j < 2; j++) {
                    gl_lds16(kSrc[j] + (size_t)kn2 * 1024, &K_lds[cur ^ 1][dstU[j]]);
                    gl_lds16(vSrc[j] + kn2, &V_lds[cur ^ 1][dstU[j]]);
                }
            }

            const char* Kt = (const char*)K_lds[cur];
            const char* Vl = (const char*)V_lds[cur];

            // ---- K fragments from LDS ----
            bf16x8 kf0[4], kf1[4];
#pragma unroll
            for (int kc = 0; kc < 4; kc++) {
                const int kcst = 4096 * (kc >> 1) + 512 * (kc & 1);
                kf0[kc] = *(const bf16x8*)(Kt + kb0 + kcst);
                kf1[kc] = *(const bf16x8*)(Kt + kb1 + kcst);
            }

            // ---- QK^T (swapped: A=K, B=Q) -> s[kc][r] = S[q=l15][kv] ----
            f32x4 s[4];
#pragma unroll
            for (int kc = 0; kc < 4; kc++) {
                f32x4 z = {};
                z = __builtin_amdgcn_mfma_f32_16x16x32_bf16(kf0[kc], qf0, z, 0, 0, 0);
                z = __builtin_amdgcn_mfma_f32_16x16x32_bf16(kf1[kc], qf1, z, 0, 0, 0);
                s[kc] = z;
            }

            // ---- causal mask (diagonal tile only) ----
            if (kt == ktend) {
#pragma unroll
                for (int kc = 0; kc < 4; kc++)
#pragma unroll
                    for (int r = 0; r < 4; r++) {
                        int kv = kn + ((kc >> 1) << 5) + (lg << 3) + ((kc & 1) << 2) + r;
                        s[kc][r] = (kv <= qrow) ? s[kc][r] : -INFINITY;
                    }
            }

            // ---- row max (15 in-reg + 2 shfl) ----
            float pm = s[0][0];
#pragma unroll
            for (int kc = 0; kc < 4; kc++)
#pragma unroll
                for (int r = 0; r < 4; r++) pm = fmaxf(pm, s[kc][r]);
            pm = fmaxf(pm, __shfl_xor(pm, 16, 64));
            pm = fmaxf(pm, __shfl_xor(pm, 32, 64));

            // ---- exact defer-max rescale ----
            if (!__all(pm <= m)) {
                float mn = fmaxf(m, pm);
                float sc = __expf((m - mn) * 0.125f);   // first tile: 0
                m = mn;
                lacc *= sc;
                float scr[4];
#pragma unroll
                for (int r = 0; r < 4; r++) scr[r] = __shfl(sc, (lg << 2) + r, 64);
#pragma unroll
                for (int dt = 0; dt < 4; dt++)
#pragma unroll
                    for (int r = 0; r < 4; r++) ao[dt][r] *= scr[r];
            }

            // ---- exp, in-lane partial sum, pack P in A-frag order ----
            const float nb = -m * 0.125f;
            float ps = 0.f;
            bf16x8 pf0, pf1;
#pragma unroll
            for (int r = 0; r < 4; r++) {
                float p0 = __expf(fmaf(s[0][r], 0.125f, nb));
                float p1 = __expf(fmaf(s[1][r], 0.125f, nb));
                float p2 = __expf(fmaf(s[2][r], 0.125f, nb));
                float p3 = __expf(fmaf(s[3][r], 0.125f, nb));
                ps += (p0 + p1) + (p2 + p3);
                pf0[r]     = (__bf16)p0;
                pf0[4 + r] = (__bf16)p1;
                pf1[r]     = (__bf16)p2;
                pf1[4 + r] = (__bf16)p3;
            }
            lacc += ps;

            // ---- PV (V fragments straight from LDS) ----
#pragma unroll
            for (int dt = 0; dt < 4; dt++) {
                bf16x8 vf0 = *(const bf16x8*)(Vl + vb0 + dt * 2048);
                bf16x8 vf1 = *(const bf16x8*)(Vl + vb1 + dt * 2048);
                ao[dt] = __builtin_amdgcn_mfma_f32_16x16x32_bf16(pf0, vf0, ao[dt], 0, 0, 0);
                ao[dt] = __builtin_amdgcn_mfma_f32_16x16x32_bf16(pf1, vf1, ao[dt], 0, 0, 0);
            }

            __syncthreads();
            cur ^= 1;
        }

        // ---- epilogue ----
        lacc += __shfl_xor(lacc, 16, 64);
        lacc += __shfl_xor(lacc, 32, 64);
        float inv = 1.0f / lacc;
        float invr[4];
#pragma unroll
        for (int r = 0; r < 4; r++) invr[r] = __shfl(inv, (lg << 2) + r, 64);
        ushort* ob = O + (size_t)(b * S_LEN + q0 + lg * 4) * HID + h * 64 + l15;
#pragma unroll
        for (int dt = 0; dt < 4; dt++)
#pragma unroll
            for (int r = 0; r < 4; r++)
                ob[(size_t)r * HID + dt * 16] = f2b(ao[dt][r] * invr[r]);
    }
}

// ---------------- launch ----------------
extern "C" void kernel_launch(void* const* d_in, const int* in_sizes, int n_in,
                              void* d_out, int out_size, void* d_ws, size_t ws_size,
                              hipStream_t stream) {
    const float* hidden = (const float*)d_in[0];
    const float* Wq = (const float*)d_in[1];
    const float* Wk = (const float*)d_in[2];
    const float* Wv = (const float*)d_in[3];
    const float* Wo = (const float*)d_in[4];

    char* ws = (char*)d_ws;
    size_t off = 0;
    auto alloc = [&](size_t bytes) -> void* {
        void* p = ws + off;
        off += (bytes + 255) & ~(size_t)255;
        return p;
    };
    ushort* hb  = (ushort*)alloc((size_t)NTOK * HID * 2);
    ushort* wq  = (ushort*)alloc((size_t)2048 * 2048 * 2);
    ushort* wkv = (ushort*)alloc((size_t)1024 * 2048 * 2);
    ushort* wo  = (ushort*)alloc((size_t)2048 * 2048 * 2);
    ushort* Qb  = (ushort*)alloc((size_t)NTOK * 2048 * 2);
    ushort* KVb = (ushort*)alloc((size_t)NTOK * 1024 * 2);
    ushort* Vtb = (ushort*)alloc((size_t)NTOK * 512 * 2);
    ushort* AO  = (ushort*)alloc((size_t)NTOK * 2048 * 2);

    auto cvt = [&](const float* in, ushort* out, int n) {
        int n4 = n / 4;
        cvt_f32_bf16<<<(n4 + 255) / 256, 256, 0, stream>>>(in, out, n4);
    };
    cvt(hidden, hb, NTOK * HID);
    cvt(Wq, wq, 2048 * 2048);
    cvt(Wk, wkv, 512 * 2048);
    cvt(Wv, wkv + (size_t)512 * 2048, 512 * 2048);
    cvt(Wo, wo, 2048 * 2048);

    gemm_bt<0><<<dim3(16, 32), 256, 0, stream>>>(hb, wq, Qb, NTOK, 2048, 2048);
    gemm_bt<0><<<dim3(8, 32), 256, 0, stream>>>(hb, wkv, KVb, NTOK, 1024, 2048);

    rope_k<<<(NTOK * NH * 32 + 255) / 256, 256, 0, stream>>>(Qb, NH, 2048, NTOK * NH * 32);
    rope_k<<<(NTOK * NKV * 32 + 255) / 256, 256, 0, stream>>>(KVb, NKV, 1024, NTOK * NKV * 32);
    transpose_v<<<dim3(S_LEN / 32, 2, BATCH * NKV), 256, 0, stream>>>(KVb, Vtb);

    attn_k<<<dim3(16, BATCH * NH), 256, 0, stream>>>(Qb, KVb, Vtb, AO);

    gemm_bt<1><<<dim3(16, 32), 256, 0, stream>>>(AO, wo, d_out, NTOK, 2048, 2048);
}

// Round 7
// 224.223 us; speedup vs baseline: 1.9366x; 1.1950x over previous
//
#include <hip/hip_runtime.h>

#define S_LEN 2048
#define BATCH 2
#define NH 32
#define NKV 8
#define HD 64
#define HID 2048
#define NTOK (BATCH * S_LEN)   // 4096
#define NQKV 3072              // 2048 Q + 512 K + 512 V
#define SC_Q 0.18033688011112042f   // 0.125 * log2(e)

typedef __attribute__((ext_vector_type(8))) __bf16 bf16x8;
typedef __attribute__((ext_vector_type(4))) float f32x4;

__device__ inline ushort f2b(float f) {
    union { float f; unsigned u; } x{f};
    unsigned r = (x.u + 0x7fff + ((x.u >> 16) & 1)) >> 16;
    return (ushort)r;
}

// ---------------- fused fp32 -> bf16 conversion (all 5 inputs, 1 launch) ----------------
// block = 256 float4s. segments (in blocks): hidden 8192, wq 4096, wk 1024, wv 1024, wo 4096
__global__ __launch_bounds__(256) void cvt_all(const float* __restrict__ hidden,
                                               const float* __restrict__ Wq,
                                               const float* __restrict__ Wk,
                                               const float* __restrict__ Wv,
                                               const float* __restrict__ Wo,
                                               ushort* __restrict__ hb,
                                               ushort* __restrict__ wqkv,
                                               ushort* __restrict__ wo) {
    int bid = blockIdx.x;
    const float* src;
    ushort* dst;
    int off;
    if (bid < 8192)        { src = hidden; dst = hb;                              off = bid; }
    else if (bid < 12288)  { src = Wq;     dst = wqkv;                            off = bid - 8192; }
    else if (bid < 13312)  { src = Wk;     dst = wqkv + (size_t)2048 * 2048;      off = bid - 12288; }
    else if (bid < 14336)  { src = Wv;     dst = wqkv + (size_t)2560 * 2048;      off = bid - 13312; }
    else                   { src = Wo;     dst = wo;                              off = bid - 14336; }
    size_t i = (size_t)off * 256 + threadIdx.x;
    float4 v = reinterpret_cast<const float4*>(src)[i];
    ushort4 o;
    o.x = f2b(v.x); o.y = f2b(v.y); o.z = f2b(v.z); o.w = f2b(v.w);
    reinterpret_cast<ushort4*>(dst)[i] = o;
}

// ---------------- global -> LDS async helper ----------------
__device__ inline void gl_lds16(const void* g, void* l) {
    __builtin_amdgcn_global_load_lds((const __attribute__((address_space(1))) void*)g,
                                     (__attribute__((address_space(3))) void*)l, 16, 0, 0);
}

// ---------------- GEMM: C[m][n] = sum_k A[m][k] * B[n][k] ----------------
// ROPE=1: apply RoPE in-register to Q/K head columns and fold SC_Q into Q.
template<int WF32, int ROPE>
__global__ __launch_bounds__(256) void gemm_bt(const ushort* __restrict__ A,
                                               const ushort* __restrict__ B,
                                               void* __restrict__ C,
                                               int M, int N, int K) {
    __shared__ __align__(16) ushort As[128 * 32];
    __shared__ __align__(16) ushort Bs[128 * 32];
    const int tid = threadIdx.x, lane = tid & 63, w = tid >> 6;
    const int wr = w >> 1, wc = w & 1, l15 = lane & 15, lg = lane >> 4;
    const int m0 = blockIdx.y * 128, n0 = blockIdx.x * 128;

    const ushort* Ag = A + (size_t)(m0 + (tid >> 2)) * K + (tid & 3) * 8;
    const ushort* Bg = B + (size_t)(n0 + (tid >> 2)) * K + (tid & 3) * 8;
    ushort* lA = As + w * 512;
    ushort* lB = Bs + w * 512;

    f32x4 acc[4][4] = {};

    for (int k0 = 0; k0 < K; k0 += 32) {
        __syncthreads();
        gl_lds16(Ag + k0, lA);
        gl_lds16(Ag + (size_t)64 * K + k0, lA + 2048);
        gl_lds16(Bg + k0, lB);
        gl_lds16(Bg + (size_t)64 * K + k0, lB + 2048);
        __syncthreads();

        const ushort* pa = As + (wr * 64 + l15) * 32 + lg * 8;
        const ushort* pb = Bs + (wc * 64 + l15) * 32 + lg * 8;
        bf16x8 af[4], bff[4];
#pragma unroll
        for (int i = 0; i < 4; i++) {
            af[i]  = *(const bf16x8*)(pa + i * 512);
            bff[i] = *(const bf16x8*)(pb + i * 512);
        }
#pragma unroll
        for (int i = 0; i < 4; i++)
#pragma unroll
            for (int j = 0; j < 4; j++)
                acc[i][j] = __builtin_amdgcn_mfma_f32_16x16x32_bf16(af[i], bff[j], acc[i][j], 0, 0, 0);
    }

    const int mr = m0 + wr * 64 + lg * 4, nc = n0 + wc * 64 + l15;

    if (ROPE) {
        const int hq = (n0 + wc * 64) >> 6;    // 0..31 Q, 32..39 K, 40..47 V
        if (hq < 40) {
            const bool isQ = hq < 32;
            // inv_freq(d) = 10000^(-d/32) = 2^(-d*log2(10000)/32); fd(16+l15) = fd(l15)*0.01
            const float fd0 = exp2f(-(float)l15 * 0.4152410118609203f);
            const float fd1 = fd0 * 0.01f;
#pragma unroll
            for (int i = 0; i < 4; i++)
#pragma unroll
                for (int r = 0; r < 4; r++) {
                    float pos = (float)((mr + i * 16 + r) & (S_LEN - 1));
#pragma unroll
                    for (int jj = 0; jj < 2; jj++) {
                        float ang = pos * (jj ? fd1 : fd0);
                        float sv, cv;
                        __sincosf(ang, &sv, &cv);
                        float x1 = acc[i][jj][r], x2 = acc[i][jj + 2][r];
                        float y0 = x1 * cv - x2 * sv;
                        float y1 = x2 * cv + x1 * sv;
                        if (isQ) { y0 *= SC_Q; y1 *= SC_Q; }
                        acc[i][jj][r] = y0;
                        acc[i][jj + 2][r] = y1;
                    }
                }
        }
    }

#pragma unroll
    for (int i = 0; i < 4; i++)
#pragma unroll
        for (int j = 0; j < 4; j++)
#pragma unroll
            for (int r = 0; r < 4; r++) {
                size_t row = mr + i * 16 + r, col = nc + j * 16;
                if (WF32) ((float*)C)[row * N + col] = acc[i][j][r];
                else      ((ushort*)C)[row * N + col] = f2b(acc[i][j][r]);
            }
}

// ---------------- V transpose: from QKV buffer (stride 3072, V at +2560) ----------------
__global__ __launch_bounds__(256) void transpose_v(const ushort* __restrict__ QKV,
                                                   ushort* __restrict__ Vt) {
    __shared__ ushort tile[32][33];
    int bz = blockIdx.z, b = bz >> 3, kvh = bz & 7;
    int s0 = blockIdx.x * 32, d0 = blockIdx.y * 32;
    int tx = threadIdx.x & 31, ty = threadIdx.x >> 5;
#pragma unroll
    for (int i = 0; i < 4; i++)
        tile[ty + i * 8][tx] = QKV[(size_t)(b * S_LEN + s0 + ty + i * 8) * NQKV + 2560 + kvh * 64 + d0 + tx];
    __syncthreads();
#pragma unroll
    for (int i = 0; i < 4; i++)
        Vt[((size_t)((b * 8 + kvh) * 64 + d0 + ty + i * 8)) * S_LEN + s0 + tx] = tile[tx][ty + i * 8];
}

// ---------------- Flash attention (causal, GQA) ----------------
// Q pre-scaled by 0.125*log2(e) and roped (GEMM epilogue); scores in log2 domain.
// Block = 4 waves = 64 q rows, one (b,h). K/V tiles staged in LDS (dbuf, swizzled).
__global__ __launch_bounds__(256) void attn_k(const ushort* __restrict__ QKV,  // stride 3072; K at +2048
                                              const ushort* __restrict__ Vt,
                                              ushort* __restrict__ O) {
    __shared__ __align__(16) ushort K_lds[2][4096];
    __shared__ __align__(16) ushort V_lds[2][4096];
    const int lane = threadIdx.x & 63, w = threadIdx.x >> 6;
    const int l15 = lane & 15, lg = lane >> 4;
    const int bh = blockIdx.y, b = bh >> 5, h = bh & 31, kvh = h >> 2;

    // ---- staging: per-lane pre-swizzled global sources ----
    const ushort* kSrc[2];
    const ushort* vSrc[2];
    int dstU[2];
#pragma unroll
    for (int j = 0; j < 2; j++) {
        int u = w * 2 + j;
        int row = u * 8 + (lane >> 3);
        int po = (lane & 7) * 16;
        int fr = ((row & 3) | (((row >> 3) & 1) << 2)) << 4;
        int dus = (po ^ fr) >> 1;
        kSrc[j] = QKV + (size_t)(b * S_LEN + row) * NQKV + 2048 + kvh * 64 + dus;
        vSrc[j] = Vt + ((size_t)((b * 8 + kvh) * 64 + row)) * S_LEN + dus;
        dstU[j] = u * 512;
    }

    // ---- fragment LDS byte offsets ----
    int fr_k = ((l15 & 3) | (((l15 >> 2) & 1) << 2)) << 4;
    int kbase = 1024 * (l15 >> 2) + 128 * (l15 & 3) + ((lg * 16) ^ (fr_k & 48));
    int k6 = (fr_k >> 6) & 1;
    int kb0 = kbase + 64 * k6, kb1 = kbase + 64 * (1 - k6);
    int fr_v = ((l15 & 3) | (((l15 >> 3) & 1) << 2)) << 4;
    int vbase = 128 * l15 + ((lg * 16) ^ (fr_v & 48));
    int v6 = (fr_v >> 6) & 1;
    int vb0 = vbase + 64 * v6, vb1 = vbase + 64 * (1 - v6);

    for (int half = 0; half < 2; ++half) {
        const int bx = half ? (31 - blockIdx.x) : blockIdx.x;
        const int q0 = bx * 64 + w * 16;
        const int qrow = q0 + l15;
        const int ktend = bx;

        const ushort* qp = QKV + (size_t)(b * S_LEN + qrow) * NQKV + h * 64 + lg * 8;
        bf16x8 qf0 = *(const bf16x8*)qp;
        bf16x8 qf1 = *(const bf16x8*)(qp + 32);

        f32x4 ao[4] = {};
        float m = -INFINITY, lacc = 0.f;

#pragma unroll
        for (int j = 0; j < 2; j++) {
            gl_lds16(kSrc[j], &K_lds[0][dstU[j]]);
            gl_lds16(vSrc[j], &V_lds[0][dstU[j]]);
        }
        __syncthreads();
        int cur = 0;

        for (int kt = 0; kt <= ktend; ++kt) {
            const int kn = kt << 6;
            if (kt < ktend) {
                const int kn2 = kn + 64;
#pragma unroll
                for (int j = 0; j < 2; j++) {
                    gl_lds16(kSrc[j] + (size_t)kn2 * NQKV, &K_lds[cur ^ 1][dstU[j]]);
                    gl_lds16(vSrc[j] + kn2, &V_lds[cur ^ 1][dstU[j]]);
                }
            }

            const char* Kt = (const char*)K_lds[cur];
            const char* Vl = (const char*)V_lds[cur];

            bf16x8 kf0[4], kf1[4];
#pragma unroll
            for (int kc = 0; kc < 4; kc++) {
                const int kcst = 4096 * (kc >> 1) + 512 * (kc & 1);
                kf0[kc] = *(const bf16x8*)(Kt + kb0 + kcst);
                kf1[kc] = *(const bf16x8*)(Kt + kb1 + kcst);
            }

            // ---- QK^T (swapped: A=K, B=Q) -> s[kc][r] = S'[q=l15][kv] (log2 domain) ----
            f32x4 s[4];
#pragma unroll
            for (int kc = 0; kc < 4; kc++) {
                f32x4 z = {};
                z = __builtin_amdgcn_mfma_f32_16x16x32_bf16(kf0[kc], qf0, z, 0, 0, 0);
                z = __builtin_amdgcn_mfma_f32_16x16x32_bf16(kf1[kc], qf1, z, 0, 0, 0);
                s[kc] = z;
            }

            if (kt == ktend) {
#pragma unroll
                for (int kc = 0; kc < 4; kc++)
#pragma unroll
                    for (int r = 0; r < 4; r++) {
                        int kv = kn + ((kc >> 1) << 5) + (lg << 3) + ((kc & 1) << 2) + r;
                        s[kc][r] = (kv <= qrow) ? s[kc][r] : -INFINITY;
                    }
            }

            float pm = s[0][0];
#pragma unroll
            for (int kc = 0; kc < 4; kc++)
#pragma unroll
                for (int r = 0; r < 4; r++) pm = fmaxf(pm, s[kc][r]);
            pm = fmaxf(pm, __shfl_xor(pm, 16, 64));
            pm = fmaxf(pm, __shfl_xor(pm, 32, 64));

            if (!__all(pm <= m)) {
                float mn = fmaxf(m, pm);
                float sc = exp2f(m - mn);   // first tile: 0
                m = mn;
                lacc *= sc;
                float scr[4];
#pragma unroll
                for (int r = 0; r < 4; r++) scr[r] = __shfl(sc, (lg << 2) + r, 64);
#pragma unroll
                for (int dt = 0; dt < 4; dt++)
#pragma unroll
                    for (int r = 0; r < 4; r++) ao[dt][r] *= scr[r];
            }

            const float nb = -m;
            float ps = 0.f;
            bf16x8 pf0, pf1;
#pragma unroll
            for (int r = 0; r < 4; r++) {
                float p0 = exp2f(s[0][r] + nb);
                float p1 = exp2f(s[1][r] + nb);
                float p2 = exp2f(s[2][r] + nb);
                float p3 = exp2f(s[3][r] + nb);
                ps += (p0 + p1) + (p2 + p3);
                pf0[r]     = (__bf16)p0;
                pf0[4 + r] = (__bf16)p1;
                pf1[r]     = (__bf16)p2;
                pf1[4 + r] = (__bf16)p3;
            }
            lacc += ps;

#pragma unroll
            for (int dt = 0; dt < 4; dt++) {
                bf16x8 vf0 = *(const bf16x8*)(Vl + vb0 + dt * 2048);
                bf16x8 vf1 = *(const bf16x8*)(Vl + vb1 + dt * 2048);
                ao[dt] = __builtin_amdgcn_mfma_f32_16x16x32_bf16(pf0, vf0, ao[dt], 0, 0, 0);
                ao[dt] = __builtin_amdgcn_mfma_f32_16x16x32_bf16(pf1, vf1, ao[dt], 0, 0, 0);
            }

            __syncthreads();
            cur ^= 1;
        }

        lacc += __shfl_xor(lacc, 16, 64);
        lacc += __shfl_xor(lacc, 32, 64);
        float inv = 1.0f / lacc;
        float invr[4];
#pragma unroll
        for (int r = 0; r < 4; r++) invr[r] = __shfl(inv, (lg << 2) + r, 64);
        ushort* ob = O + (size_t)(b * S_LEN + q0 + lg * 4) * HID + h * 64 + l15;
#pragma unroll
        for (int dt = 0; dt < 4; dt++)
#pragma unroll
            for (int r = 0; r < 4; r++) {
                union { __bf16 h; ushort u; } cv{(__bf16)(ao[dt][r] * invr[r])};
                ob[(size_t)r * HID + dt * 16] = cv.u;
            }
    }
}

// ---------------- launch ----------------
extern "C" void kernel_launch(void* const* d_in, const int* in_sizes, int n_in,
                              void* d_out, int out_size, void* d_ws, size_t ws_size,
                              hipStream_t stream) {
    const float* hidden = (const float*)d_in[0];
    const float* Wq = (const float*)d_in[1];
    const float* Wk = (const float*)d_in[2];
    const float* Wv = (const float*)d_in[3];
    const float* Wo = (const float*)d_in[4];

    char* ws = (char*)d_ws;
    size_t off = 0;
    auto alloc = [&](size_t bytes) -> void* {
        void* p = ws + off;
        off += (bytes + 255) & ~(size_t)255;
        return p;
    };
    ushort* hb   = (ushort*)alloc((size_t)NTOK * HID * 2);
    ushort* wqkv = (ushort*)alloc((size_t)NQKV * 2048 * 2);
    ushort* wo   = (ushort*)alloc((size_t)2048 * 2048 * 2);
    ushort* QKVb = (ushort*)alloc((size_t)NTOK * NQKV * 2);
    ushort* Vtb  = (ushort*)alloc((size_t)NTOK * 512 * 2);
    ushort* AO   = (ushort*)alloc((size_t)NTOK * 2048 * 2);

    cvt_all<<<18432, 256, 0, stream>>>(hidden, Wq, Wk, Wv, Wo, hb, wqkv, wo);

    gemm_bt<0, 1><<<dim3(24, 32), 256, 0, stream>>>(hb, wqkv, QKVb, NTOK, NQKV, 2048);

    transpose_v<<<dim3(S_LEN / 32, 2, BATCH * NKV), 256, 0, stream>>>(QKVb, Vtb);

    attn_k<<<dim3(16, BATCH * NH), 256, 0, stream>>>(QKVb, Vtb, AO);

    gemm_bt<1, 0><<<dim3(16, 32), 256, 0, stream>>>(AO, wo, d_out, NTOK, 2048, 2048);
}

// Round 8
// 210.886 us; speedup vs baseline: 2.0591x; 1.0632x over previous
//
#include <hip/hip_runtime.h>

#define S_LEN 2048
#define BATCH 2
#define NH 32
#define NKV 8
#define HD 64
#define HID 2048
#define NTOK (BATCH * S_LEN)   // 4096
#define NQKV 3072              // 2048 Q + 512 K + 512 V
#define SC_Q 0.18033688011112042f   // 0.125 * log2(e)

typedef __attribute__((ext_vector_type(8))) __bf16 bf16x8;
typedef __attribute__((ext_vector_type(4))) float f32x4;

__device__ inline ushort f2b(float f) {
    union { float f; unsigned u; } x{f};
    unsigned r = (x.u + 0x7fff + ((x.u >> 16) & 1)) >> 16;
    return (ushort)r;
}
__device__ inline float ex2(float x) { return __builtin_amdgcn_exp2f(x); }  // raw v_exp_f32

// ---------------- fused fp32 -> bf16 conversion (all 5 inputs, 1 launch) ----------------
__global__ __launch_bounds__(256) void cvt_all(const float* __restrict__ hidden,
                                               const float* __restrict__ Wq,
                                               const float* __restrict__ Wk,
                                               const float* __restrict__ Wv,
                                               const float* __restrict__ Wo,
                                               ushort* __restrict__ hb,
                                               ushort* __restrict__ wqkv,
                                               ushort* __restrict__ wo) {
    int bid = blockIdx.x;
    const float* src;
    ushort* dst;
    int off;
    if (bid < 8192)        { src = hidden; dst = hb;                              off = bid; }
    else if (bid < 12288)  { src = Wq;     dst = wqkv;                            off = bid - 8192; }
    else if (bid < 13312)  { src = Wk;     dst = wqkv + (size_t)2048 * 2048;      off = bid - 12288; }
    else if (bid < 14336)  { src = Wv;     dst = wqkv + (size_t)2560 * 2048;      off = bid - 13312; }
    else                   { src = Wo;     dst = wo;                              off = bid - 14336; }
    size_t i = (size_t)off * 256 + threadIdx.x;
    float4 v = reinterpret_cast<const float4*>(src)[i];
    ushort4 o;
    o.x = f2b(v.x); o.y = f2b(v.y); o.z = f2b(v.z); o.w = f2b(v.w);
    reinterpret_cast<ushort4*>(dst)[i] = o;
}

// ---------------- global -> LDS async helper ----------------
__device__ inline void gl_lds16(const void* g, void* l) {
    __builtin_amdgcn_global_load_lds((const __attribute__((address_space(1))) void*)g,
                                     (__attribute__((address_space(3))) void*)l, 16, 0, 0);
}

// ---------------- GEMM: C[m][n] = sum_k A[m][k] * B[n][k] ----------------
// ROPE=1: rope+scale Q/K in-register; route head-aligned column blocks to
// compact per-tensor buffers: Q->C (stride 2048), K->Kd (512), V->Vd (512).
template<int WF32, int ROPE>
__global__ __launch_bounds__(256) void gemm_bt(const ushort* __restrict__ A,
                                               const ushort* __restrict__ B,
                                               void* __restrict__ C,
                                               ushort* __restrict__ Kd,
                                               ushort* __restrict__ Vd,
                                               int M, int N, int K) {
    __shared__ __align__(16) ushort As[128 * 32];
    __shared__ __align__(16) ushort Bs[128 * 32];
    const int tid = threadIdx.x, lane = tid & 63, w = tid >> 6;
    const int wr = w >> 1, wc = w & 1, l15 = lane & 15, lg = lane >> 4;
    const int m0 = blockIdx.y * 128, n0 = blockIdx.x * 128;

    const ushort* Ag = A + (size_t)(m0 + (tid >> 2)) * K + (tid & 3) * 8;
    const ushort* Bg = B + (size_t)(n0 + (tid >> 2)) * K + (tid & 3) * 8;
    ushort* lA = As + w * 512;
    ushort* lB = Bs + w * 512;

    f32x4 acc[4][4] = {};

    for (int k0 = 0; k0 < K; k0 += 32) {
        __syncthreads();
        gl_lds16(Ag + k0, lA);
        gl_lds16(Ag + (size_t)64 * K + k0, lA + 2048);
        gl_lds16(Bg + k0, lB);
        gl_lds16(Bg + (size_t)64 * K + k0, lB + 2048);
        __syncthreads();

        const ushort* pa = As + (wr * 64 + l15) * 32 + lg * 8;
        const ushort* pb = Bs + (wc * 64 + l15) * 32 + lg * 8;
        bf16x8 af[4], bff[4];
#pragma unroll
        for (int i = 0; i < 4; i++) {
            af[i]  = *(const bf16x8*)(pa + i * 512);
            bff[i] = *(const bf16x8*)(pb + i * 512);
        }
#pragma unroll
        for (int i = 0; i < 4; i++)
#pragma unroll
            for (int j = 0; j < 4; j++)
                acc[i][j] = __builtin_amdgcn_mfma_f32_16x16x32_bf16(af[i], bff[j], acc[i][j], 0, 0, 0);
    }

    const int mr = m0 + wr * 64 + lg * 4, nc = n0 + wc * 64 + l15;

    if (!ROPE) {
#pragma unroll
        for (int i = 0; i < 4; i++)
#pragma unroll
            for (int j = 0; j < 4; j++)
#pragma unroll
                for (int r = 0; r < 4; r++) {
                    size_t row = mr + i * 16 + r, col = nc + j * 16;
                    if (WF32) ((float*)C)[row * N + col] = acc[i][j][r];
                    else      ((ushort*)C)[row * N + col] = f2b(acc[i][j][r]);
                }
        return;
    }

    // ---- ROPE epilogue: wave-uniform head block (64 cols) ----
    const int hq = (n0 + wc * 64) >> 6;    // 0..31 Q, 32..39 K, 40..47 V
    if (hq < 40) {
        const bool isQ = hq < 32;
        const float fd0 = ex2(-(float)l15 * 0.4152410118609203f);  // 10000^(-l15/32)
        const float fd1 = fd0 * 0.01f;                             // l15+16
#pragma unroll
        for (int i = 0; i < 4; i++)
#pragma unroll
            for (int r = 0; r < 4; r++) {
                float pos = (float)((mr + i * 16 + r) & (S_LEN - 1));
#pragma unroll
                for (int jj = 0; jj < 2; jj++) {
                    float ang = pos * (jj ? fd1 : fd0);
                    float sv, cv;
                    __sincosf(ang, &sv, &cv);
                    float x1 = acc[i][jj][r], x2 = acc[i][jj + 2][r];
                    float y0 = x1 * cv - x2 * sv;
                    float y1 = x2 * cv + x1 * sv;
                    if (isQ) { y0 *= SC_Q; y1 *= SC_Q; }
                    acc[i][jj][r] = y0;
                    acc[i][jj + 2][r] = y1;
                }
            }
    }
    ushort* dst;
    int dstride, colb;
    if (hq < 32)      { dst = (ushort*)C; dstride = 2048; colb = nc; }
    else if (hq < 40) { dst = Kd;         dstride = 512;  colb = nc - 2048; }
    else              { dst = Vd;         dstride = 512;  colb = nc - 2560; }
#pragma unroll
    for (int i = 0; i < 4; i++)
#pragma unroll
        for (int j = 0; j < 4; j++)
#pragma unroll
            for (int r = 0; r < 4; r++) {
                size_t row = mr + i * 16 + r;
                dst[row * dstride + colb + j * 16] = f2b(acc[i][j][r]);
            }
}

// ---------------- V transpose: Vb [NTOK][512] -> Vt [b][kvh][64][S] ----------------
__global__ __launch_bounds__(256) void transpose_v(const ushort* __restrict__ V,
                                                   ushort* __restrict__ Vt) {
    __shared__ ushort tile[32][33];
    int bz = blockIdx.z, b = bz >> 3, kvh = bz & 7;
    int s0 = blockIdx.x * 32, d0 = blockIdx.y * 32;
    int tx = threadIdx.x & 31, ty = threadIdx.x >> 5;
#pragma unroll
    for (int i = 0; i < 4; i++)
        tile[ty + i * 8][tx] = V[(size_t)(b * S_LEN + s0 + ty + i * 8) * 512 + kvh * 64 + d0 + tx];
    __syncthreads();
#pragma unroll
    for (int i = 0; i < 4; i++)
        Vt[((size_t)((b * 8 + kvh) * 64 + d0 + ty + i * 8)) * S_LEN + s0 + tx] = tile[tx][ty + i * 8];
}

// ---------------- Flash attention (causal, GQA) ----------------
// Q pre-scaled by 0.125*log2(e) and roped; scores in log2 domain, native v_exp.
// Block = 4 waves = 64 q rows, one (b,h). K/V tiles staged in LDS (dbuf, swizzled).
__global__ __launch_bounds__(256) void attn_k(const ushort* __restrict__ Q,   // stride 2048
                                              const ushort* __restrict__ Kc,  // stride 512
                                              const ushort* __restrict__ Vt,
                                              ushort* __restrict__ O) {
    __shared__ __align__(16) ushort K_lds[2][4096];
    __shared__ __align__(16) ushort V_lds[2][4096];
    const int lane = threadIdx.x & 63, w = threadIdx.x >> 6;
    const int l15 = lane & 15, lg = lane >> 4;
    const int bh = blockIdx.y, b = bh >> 5, h = bh & 31, kvh = h >> 2;

    // ---- staging: per-lane pre-swizzled global sources ----
    const ushort* kSrc[2];
    const ushort* vSrc[2];
    int dstU[2];
#pragma unroll
    for (int j = 0; j < 2; j++) {
        int u = w * 2 + j;
        int row = u * 8 + (lane >> 3);
        int po = (lane & 7) * 16;
        int fr = ((row & 3) | (((row >> 3) & 1) << 2)) << 4;
        int dus = (po ^ fr) >> 1;
        kSrc[j] = Kc + (size_t)(b * S_LEN + row) * 512 + kvh * 64 + dus;
        vSrc[j] = Vt + ((size_t)((b * 8 + kvh) * 64 + row)) * S_LEN + dus;
        dstU[j] = u * 512;
    }

    // ---- fragment LDS byte offsets ----
    int fr_k = ((l15 & 3) | (((l15 >> 2) & 1) << 2)) << 4;
    int kbase = 1024 * (l15 >> 2) + 128 * (l15 & 3) + ((lg * 16) ^ (fr_k & 48));
    int k6 = (fr_k >> 6) & 1;
    int kb0 = kbase + 64 * k6, kb1 = kbase + 64 * (1 - k6);
    int fr_v = ((l15 & 3) | (((l15 >> 3) & 1) << 2)) << 4;
    int vbase = 128 * l15 + ((lg * 16) ^ (fr_v & 48));
    int v6 = (fr_v >> 6) & 1;
    int vb0 = vbase + 64 * v6, vb1 = vbase + 64 * (1 - v6);

    for (int half = 0; half < 2; ++half) {
        const int bx = half ? (31 - blockIdx.x) : blockIdx.x;
        const int q0 = bx * 64 + w * 16;
        const int qrow = q0 + l15;
        const int ktend = bx;

        const ushort* qp = Q + (size_t)(b * S_LEN + qrow) * HID + h * 64 + lg * 8;
        bf16x8 qf0 = *(const bf16x8*)qp;
        bf16x8 qf1 = *(const bf16x8*)(qp + 32);

        f32x4 ao[4] = {};
        float m = -INFINITY, lacc = 0.f;

#pragma unroll
        for (int j = 0; j < 2; j++) {
            gl_lds16(kSrc[j], &K_lds[0][dstU[j]]);
            gl_lds16(vSrc[j], &V_lds[0][dstU[j]]);
        }
        __syncthreads();
        int cur = 0;

        for (int kt = 0; kt <= ktend; ++kt) {
            const int kn = kt << 6;
            if (kt < ktend) {
                const int kn2 = kn + 64;
#pragma unroll
                for (int j = 0; j < 2; j++) {
                    gl_lds16(kSrc[j] + (size_t)kn2 * 512, &K_lds[cur ^ 1][dstU[j]]);
                    gl_lds16(vSrc[j] + kn2, &V_lds[cur ^ 1][dstU[j]]);
                }
            }

            const char* Kt = (const char*)K_lds[cur];
            const char* Vl = (const char*)V_lds[cur];

            bf16x8 kf0[4], kf1[4];
#pragma unroll
            for (int kc = 0; kc < 4; kc++) {
                const int kcst = 4096 * (kc >> 1) + 512 * (kc & 1);
                kf0[kc] = *(const bf16x8*)(Kt + kb0 + kcst);
                kf1[kc] = *(const bf16x8*)(Kt + kb1 + kcst);
            }

            // ---- QK^T (swapped: A=K, B=Q) -> s[kc][r] = S'[q=l15][kv] (log2 domain) ----
            f32x4 s[4];
#pragma unroll
            for (int kc = 0; kc < 4; kc++) {
                f32x4 z = {};
                z = __builtin_amdgcn_mfma_f32_16x16x32_bf16(kf0[kc], qf0, z, 0, 0, 0);
                z = __builtin_amdgcn_mfma_f32_16x16x32_bf16(kf1[kc], qf1, z, 0, 0, 0);
                s[kc] = z;
            }

            if (kt == ktend) {
#pragma unroll
                for (int kc = 0; kc < 4; kc++)
#pragma unroll
                    for (int r = 0; r < 4; r++) {
                        int kv = kn + ((kc >> 1) << 5) + (lg << 3) + ((kc & 1) << 2) + r;
                        s[kc][r] = (kv <= qrow) ? s[kc][r] : -INFINITY;
                    }
            }

            float pm = s[0][0];
#pragma unroll
            for (int kc = 0; kc < 4; kc++)
#pragma unroll
                for (int r = 0; r < 4; r++) pm = fmaxf(pm, s[kc][r]);
            pm = fmaxf(pm, __shfl_xor(pm, 16, 64));
            pm = fmaxf(pm, __shfl_xor(pm, 32, 64));

            if (!__all(pm <= m)) {
                float mn = fmaxf(m, pm);
                float sc = ex2(m - mn);   // first tile: exp2(-inf)=0
                m = mn;
                lacc *= sc;
                float scr[4];
#pragma unroll
                for (int r = 0; r < 4; r++) scr[r] = __shfl(sc, (lg << 2) + r, 64);
#pragma unroll
                for (int dt = 0; dt < 4; dt++)
#pragma unroll
                    for (int r = 0; r < 4; r++) ao[dt][r] *= scr[r];
            }

            const float nb = -m;
            float ps = 0.f;
            bf16x8 pf0, pf1;
#pragma unroll
            for (int r = 0; r < 4; r++) {
                float p0 = ex2(s[0][r] + nb);
                float p1 = ex2(s[1][r] + nb);
                float p2 = ex2(s[2][r] + nb);
                float p3 = ex2(s[3][r] + nb);
                ps += (p0 + p1) + (p2 + p3);
                pf0[r]     = (__bf16)p0;
                pf0[4 + r] = (__bf16)p1;
                pf1[r]     = (__bf16)p2;
                pf1[4 + r] = (__bf16)p3;
            }
            lacc += ps;

#pragma unroll
            for (int dt = 0; dt < 4; dt++) {
                bf16x8 vf0 = *(const bf16x8*)(Vl + vb0 + dt * 2048);
                bf16x8 vf1 = *(const bf16x8*)(Vl + vb1 + dt * 2048);
                ao[dt] = __builtin_amdgcn_mfma_f32_16x16x32_bf16(pf0, vf0, ao[dt], 0, 0, 0);
                ao[dt] = __builtin_amdgcn_mfma_f32_16x16x32_bf16(pf1, vf1, ao[dt], 0, 0, 0);
            }

            __syncthreads();
            cur ^= 1;
        }

        lacc += __shfl_xor(lacc, 16, 64);
        lacc += __shfl_xor(lacc, 32, 64);
        float inv = 1.0f / lacc;
        float invr[4];
#pragma unroll
        for (int r = 0; r < 4; r++) invr[r] = __shfl(inv, (lg << 2) + r, 64);
        ushort* ob = O + (size_t)(b * S_LEN + q0 + lg * 4) * HID + h * 64 + l15;
#pragma unroll
        for (int dt = 0; dt < 4; dt++)
#pragma unroll
            for (int r = 0; r < 4; r++) {
                union { __bf16 h; ushort u; } cv{(__bf16)(ao[dt][r] * invr[r])};
                ob[(size_t)r * HID + dt * 16] = cv.u;
            }
    }
}

// ---------------- launch ----------------
extern "C" void kernel_launch(void* const* d_in, const int* in_sizes, int n_in,
                              void* d_out, int out_size, void* d_ws, size_t ws_size,
                              hipStream_t stream) {
    const float* hidden = (const float*)d_in[0];
    const float* Wq = (const float*)d_in[1];
    const float* Wk = (const float*)d_in[2];
    const float* Wv = (const float*)d_in[3];
    const float* Wo = (const float*)d_in[4];

    char* ws = (char*)d_ws;
    size_t off = 0;
    auto alloc = [&](size_t bytes) -> void* {
        void* p = ws + off;
        off += (bytes + 255) & ~(size_t)255;
        return p;
    };
    ushort* hb   = (ushort*)alloc((size_t)NTOK * HID * 2);
    ushort* wqkv = (ushort*)alloc((size_t)NQKV * 2048 * 2);
    ushort* wo   = (ushort*)alloc((size_t)2048 * 2048 * 2);
    ushort* Qb   = (ushort*)alloc((size_t)NTOK * 2048 * 2);
    ushort* Kb   = (ushort*)alloc((size_t)NTOK * 512 * 2);
    ushort* Vb   = (ushort*)alloc((size_t)NTOK * 512 * 2);
    ushort* Vtb  = (ushort*)alloc((size_t)NTOK * 512 * 2);
    ushort* AO   = (ushort*)alloc((size_t)NTOK * 2048 * 2);

    cvt_all<<<18432, 256, 0, stream>>>(hidden, Wq, Wk, Wv, Wo, hb, wqkv, wo);

    gemm_bt<0, 1><<<dim3(24, 32), 256, 0, stream>>>(hb, wqkv, Qb, Kb, Vb, NTOK, NQKV, 2048);

    transpose_v<<<dim3(S_LEN / 32, 2, BATCH * NKV), 256, 0, stream>>>(Vb, Vtb);

    attn_k<<<dim3(16, BATCH * NH), 256, 0, stream>>>(Qb, Kb, Vtb, AO);

    gemm_bt<1, 0><<<dim3(16, 32), 256, 0, stream>>>(AO, wo, d_out, nullptr, nullptr, NTOK, 2048, 2048);
}

// Round 9
// 205.188 us; speedup vs baseline: 2.1163x; 1.0278x over previous
//
#include <hip/hip_runtime.h>

#define S_LEN 2048
#define BATCH 2
#define NH 32
#define NKV 8
#define HD 64
#define HID 2048
#define NTOK (BATCH * S_LEN)   // 4096
#define NQKV 3072              // 2048 Q + 512 K + 512 V
#define SC_Q 0.18033688011112042f   // 0.125 * log2(e)

typedef __attribute__((ext_vector_type(8))) __bf16 bf16x8;
typedef __attribute__((ext_vector_type(4))) float f32x4;

__device__ inline ushort f2b(float f) {
    union { float f; unsigned u; } x{f};
    unsigned r = (x.u + 0x7fff + ((x.u >> 16) & 1)) >> 16;
    return (ushort)r;
}
__device__ inline float ex2(float x) { return __builtin_amdgcn_exp2f(x); }  // raw v_exp_f32

// ---------------- fused fp32 -> bf16 conversion (all 5 inputs, 1 launch) ----------------
__global__ __launch_bounds__(256) void cvt_all(const float* __restrict__ hidden,
                                               const float* __restrict__ Wq,
                                               const float* __restrict__ Wk,
                                               const float* __restrict__ Wv,
                                               const float* __restrict__ Wo,
                                               ushort* __restrict__ hb,
                                               ushort* __restrict__ wqkv,
                                               ushort* __restrict__ wo) {
    int bid = blockIdx.x;
    const float* src;
    ushort* dst;
    int off;
    if (bid < 8192)        { src = hidden; dst = hb;                              off = bid; }
    else if (bid < 12288)  { src = Wq;     dst = wqkv;                            off = bid - 8192; }
    else if (bid < 13312)  { src = Wk;     dst = wqkv + (size_t)2048 * 2048;      off = bid - 12288; }
    else if (bid < 14336)  { src = Wv;     dst = wqkv + (size_t)2560 * 2048;      off = bid - 13312; }
    else                   { src = Wo;     dst = wo;                              off = bid - 14336; }
    size_t i = (size_t)off * 256 + threadIdx.x;
    float4 v = reinterpret_cast<const float4*>(src)[i];
    ushort4 o;
    o.x = f2b(v.x); o.y = f2b(v.y); o.z = f2b(v.z); o.w = f2b(v.w);
    reinterpret_cast<ushort4*>(dst)[i] = o;
}

// ---------------- global -> LDS async helper ----------------
__device__ inline void gl_lds16(const void* g, void* l) {
    __builtin_amdgcn_global_load_lds((const __attribute__((address_space(1))) void*)g,
                                     (__attribute__((address_space(3))) void*)l, 16, 0, 0);
}

// ---------------- GEMM: C[m][n] = sum_k A[m][k] * B[n][k] ----------------
// XCD-aware block swizzle (nwg % 8 == 0 for all call sites).
// ROPE=1: rope+scale Q/K in-register; route head blocks to compact buffers.
template<int WF32, int ROPE>
__global__ __launch_bounds__(256) void gemm_bt(const ushort* __restrict__ A,
                                               const ushort* __restrict__ B,
                                               void* __restrict__ C,
                                               ushort* __restrict__ Kd,
                                               ushort* __restrict__ Vd,
                                               int M, int N, int K) {
    __shared__ __align__(16) ushort As[128 * 32];
    __shared__ __align__(16) ushort Bs[128 * 32];
    const int tid = threadIdx.x, lane = tid & 63, w = tid >> 6;
    const int wr = w >> 1, wc = w & 1, l15 = lane & 15, lg = lane >> 4;

    const int nbx = gridDim.x;
    int lid = blockIdx.y * nbx + blockIdx.x;
    const int cpx = (nbx * gridDim.y) >> 3;
    int swz = (lid & 7) * cpx + (lid >> 3);
    const int m0 = (swz / nbx) * 128, n0 = (swz % nbx) * 128;

    const ushort* Ag = A + (size_t)(m0 + (tid >> 2)) * K + (tid & 3) * 8;
    const ushort* Bg = B + (size_t)(n0 + (tid >> 2)) * K + (tid & 3) * 8;
    ushort* lA = As + w * 512;
    ushort* lB = Bs + w * 512;

    f32x4 acc[4][4] = {};

    for (int k0 = 0; k0 < K; k0 += 32) {
        __syncthreads();
        gl_lds16(Ag + k0, lA);
        gl_lds16(Ag + (size_t)64 * K + k0, lA + 2048);
        gl_lds16(Bg + k0, lB);
        gl_lds16(Bg + (size_t)64 * K + k0, lB + 2048);
        __syncthreads();

        const ushort* pa = As + (wr * 64 + l15) * 32 + lg * 8;
        const ushort* pb = Bs + (wc * 64 + l15) * 32 + lg * 8;
        bf16x8 af[4], bff[4];
#pragma unroll
        for (int i = 0; i < 4; i++) {
            af[i]  = *(const bf16x8*)(pa + i * 512);
            bff[i] = *(const bf16x8*)(pb + i * 512);
        }
#pragma unroll
        for (int i = 0; i < 4; i++)
#pragma unroll
            for (int j = 0; j < 4; j++)
                acc[i][j] = __builtin_amdgcn_mfma_f32_16x16x32_bf16(af[i], bff[j], acc[i][j], 0, 0, 0);
    }

    const int mr = m0 + wr * 64 + lg * 4, nc = n0 + wc * 64 + l15;

    if (!ROPE) {
#pragma unroll
        for (int i = 0; i < 4; i++)
#pragma unroll
            for (int j = 0; j < 4; j++)
#pragma unroll
                for (int r = 0; r < 4; r++) {
                    size_t row = mr + i * 16 + r, col = nc + j * 16;
                    if (WF32) ((float*)C)[row * N + col] = acc[i][j][r];
                    else      ((ushort*)C)[row * N + col] = f2b(acc[i][j][r]);
                }
        return;
    }

    // ---- ROPE epilogue: wave-uniform head block (64 cols) ----
    const int hq = (n0 + wc * 64) >> 6;    // 0..31 Q, 32..39 K, 40..47 V
    if (hq < 40) {
        const bool isQ = hq < 32;
        const float fd0 = ex2(-(float)l15 * 0.4152410118609203f);  // 10000^(-l15/32)
        const float fd1 = fd0 * 0.01f;                             // l15+16
#pragma unroll
        for (int i = 0; i < 4; i++)
#pragma unroll
            for (int r = 0; r < 4; r++) {
                float pos = (float)((mr + i * 16 + r) & (S_LEN - 1));
#pragma unroll
                for (int jj = 0; jj < 2; jj++) {
                    float ang = pos * (jj ? fd1 : fd0);
                    float sv, cv;
                    __sincosf(ang, &sv, &cv);
                    float x1 = acc[i][jj][r], x2 = acc[i][jj + 2][r];
                    float y0 = x1 * cv - x2 * sv;
                    float y1 = x2 * cv + x1 * sv;
                    if (isQ) { y0 *= SC_Q; y1 *= SC_Q; }
                    acc[i][jj][r] = y0;
                    acc[i][jj + 2][r] = y1;
                }
            }
    }
    ushort* dst;
    int dstride, colb;
    if (hq < 32)      { dst = (ushort*)C; dstride = 2048; colb = nc; }
    else if (hq < 40) { dst = Kd;         dstride = 512;  colb = nc - 2048; }
    else              { dst = Vd;         dstride = 512;  colb = nc - 2560; }
#pragma unroll
    for (int i = 0; i < 4; i++)
#pragma unroll
        for (int j = 0; j < 4; j++)
#pragma unroll
            for (int r = 0; r < 4; r++) {
                size_t row = mr + i * 16 + r;
                dst[row * dstride + colb + j * 16] = f2b(acc[i][j][r]);
            }
}

// ---------------- V transpose: Vb [NTOK][512] -> Vt [b][kvh][64][S] ----------------
__global__ __launch_bounds__(256) void transpose_v(const ushort* __restrict__ V,
                                                   ushort* __restrict__ Vt) {
    __shared__ ushort tile[32][33];
    int bz = blockIdx.z, b = bz >> 3, kvh = bz & 7;
    int s0 = blockIdx.x * 32, d0 = blockIdx.y * 32;
    int tx = threadIdx.x & 31, ty = threadIdx.x >> 5;
#pragma unroll
    for (int i = 0; i < 4; i++)
        tile[ty + i * 8][tx] = V[(size_t)(b * S_LEN + s0 + ty + i * 8) * 512 + kvh * 64 + d0 + tx];
    __syncthreads();
#pragma unroll
    for (int i = 0; i < 4; i++)
        Vt[((size_t)((b * 8 + kvh) * 64 + d0 + ty + i * 8)) * S_LEN + s0 + tx] = tile[tx][ty + i * 8];
}

// ---------------- Flash attention (causal, GQA) ----------------
// No online max: scores (log2 domain, pre-scaled Q) are bounded ~|7| << 127,
// so p = exp2(s) raw and normalize by the sum at the end (shift-invariance).
// Row sums accumulated via MFMA with an all-ones B fragment -> lsum lands
// directly in PV C-layout (no shuffles). K/V LDS-staged, dbuf, swizzled.
__global__ __launch_bounds__(256) void attn_k(const ushort* __restrict__ Q,   // stride 2048
                                              const ushort* __restrict__ Kc,  // stride 512
                                              const ushort* __restrict__ Vt,
                                              ushort* __restrict__ O) {
    __shared__ __align__(16) ushort K_lds[2][4096];
    __shared__ __align__(16) ushort V_lds[2][4096];
    const int lane = threadIdx.x & 63, w = threadIdx.x >> 6;
    const int l15 = lane & 15, lg = lane >> 4;

    // XCD swizzle: 1024 blocks -> 128 consecutive (bh,bx) per XCD (2 KV heads/L2)
    int lid = blockIdx.y * 16 + blockIdx.x;
    int swz = (lid & 7) * 128 + (lid >> 3);
    const int bxs = swz & 15;
    const int bh = swz >> 4;
    const int b = bh >> 5, h = bh & 31, kvh = h >> 2;

    // ---- staging: per-lane pre-swizzled global sources ----
    const ushort* kSrc[2];
    const ushort* vSrc[2];
    int dstU[2];
#pragma unroll
    for (int j = 0; j < 2; j++) {
        int u = w * 2 + j;
        int row = u * 8 + (lane >> 3);
        int po = (lane & 7) * 16;
        int fr = ((row & 3) | (((row >> 3) & 1) << 2)) << 4;
        int dus = (po ^ fr) >> 1;
        kSrc[j] = Kc + (size_t)(b * S_LEN + row) * 512 + kvh * 64 + dus;
        vSrc[j] = Vt + ((size_t)((b * 8 + kvh) * 64 + row)) * S_LEN + dus;
        dstU[j] = u * 512;
    }

    // ---- fragment LDS byte offsets ----
    int fr_k = ((l15 & 3) | (((l15 >> 2) & 1) << 2)) << 4;
    int kbase = 1024 * (l15 >> 2) + 128 * (l15 & 3) + ((lg * 16) ^ (fr_k & 48));
    int k6 = (fr_k >> 6) & 1;
    int kb0 = kbase + 64 * k6, kb1 = kbase + 64 * (1 - k6);
    int fr_v = ((l15 & 3) | (((l15 >> 3) & 1) << 2)) << 4;
    int vbase = 128 * l15 + ((lg * 16) ^ (fr_v & 48));
    int v6 = (fr_v >> 6) & 1;
    int vb0 = vbase + 64 * v6, vb1 = vbase + 64 * (1 - v6);

    // all-ones B fragment for row-sum MFMA
    bf16x8 onesf;
#pragma unroll
    for (int i = 0; i < 8; i++) onesf[i] = (__bf16)1.0f;

    for (int half = 0; half < 2; ++half) {
        const int bx = half ? (31 - bxs) : bxs;
        const int q0 = bx * 64 + w * 16;
        const int qrow = q0 + l15;
        const int ktend = bx;

        const ushort* qp = Q + (size_t)(b * S_LEN + qrow) * HID + h * 64 + lg * 8;
        bf16x8 qf0 = *(const bf16x8*)qp;
        bf16x8 qf1 = *(const bf16x8*)(qp + 32);

        f32x4 ao[4] = {};
        f32x4 lsum = {};

#pragma unroll
        for (int j = 0; j < 2; j++) {
            gl_lds16(kSrc[j], &K_lds[0][dstU[j]]);
            gl_lds16(vSrc[j], &V_lds[0][dstU[j]]);
        }
        __syncthreads();
        int cur = 0;

        for (int kt = 0; kt <= ktend; ++kt) {
            const int kn = kt << 6;
            if (kt < ktend) {
                const int kn2 = kn + 64;
#pragma unroll
                for (int j = 0; j < 2; j++) {
                    gl_lds16(kSrc[j] + (size_t)kn2 * 512, &K_lds[cur ^ 1][dstU[j]]);
                    gl_lds16(vSrc[j] + kn2, &V_lds[cur ^ 1][dstU[j]]);
                }
            }

            const char* Kt = (const char*)K_lds[cur];
            const char* Vl = (const char*)V_lds[cur];

            bf16x8 kf0[4], kf1[4];
#pragma unroll
            for (int kc = 0; kc < 4; kc++) {
                const int kcst = 4096 * (kc >> 1) + 512 * (kc & 1);
                kf0[kc] = *(const bf16x8*)(Kt + kb0 + kcst);
                kf1[kc] = *(const bf16x8*)(Kt + kb1 + kcst);
            }

            // ---- QK^T (swapped: A=K, B=Q) -> s[kc][r] = S'[q=l15][kv] (log2 domain) ----
            f32x4 s[4];
#pragma unroll
            for (int kc = 0; kc < 4; kc++) {
                f32x4 z = {};
                z = __builtin_amdgcn_mfma_f32_16x16x32_bf16(kf0[kc], qf0, z, 0, 0, 0);
                z = __builtin_amdgcn_mfma_f32_16x16x32_bf16(kf1[kc], qf1, z, 0, 0, 0);
                s[kc] = z;
            }

            if (kt == ktend) {
#pragma unroll
                for (int kc = 0; kc < 4; kc++)
#pragma unroll
                    for (int r = 0; r < 4; r++) {
                        int kv = kn + ((kc >> 1) << 5) + (lg << 3) + ((kc & 1) << 2) + r;
                        s[kc][r] = (kv <= qrow) ? s[kc][r] : -INFINITY;
                    }
            }

            // ---- p = exp2(s) raw (no max subtraction), pack in A-frag order ----
            bf16x8 pf0, pf1;
#pragma unroll
            for (int r = 0; r < 4; r++) {
                pf0[r]     = (__bf16)ex2(s[0][r]);
                pf0[4 + r] = (__bf16)ex2(s[1][r]);
                pf1[r]     = (__bf16)ex2(s[2][r]);
                pf1[4 + r] = (__bf16)ex2(s[3][r]);
            }

            // ---- row sums via MFMA-ones (lands in PV C-layout) ----
            lsum = __builtin_amdgcn_mfma_f32_16x16x32_bf16(pf0, onesf, lsum, 0, 0, 0);
            lsum = __builtin_amdgcn_mfma_f32_16x16x32_bf16(pf1, onesf, lsum, 0, 0, 0);

            // ---- PV ----
#pragma unroll
            for (int dt = 0; dt < 4; dt++) {
                bf16x8 vf0 = *(const bf16x8*)(Vl + vb0 + dt * 2048);
                bf16x8 vf1 = *(const bf16x8*)(Vl + vb1 + dt * 2048);
                ao[dt] = __builtin_amdgcn_mfma_f32_16x16x32_bf16(pf0, vf0, ao[dt], 0, 0, 0);
                ao[dt] = __builtin_amdgcn_mfma_f32_16x16x32_bf16(pf1, vf1, ao[dt], 0, 0, 0);
            }

            __syncthreads();
            cur ^= 1;
        }

        // ---- epilogue: lsum[r] is already the row sum for q-row lg*4+r ----
        float invr[4];
#pragma unroll
        for (int r = 0; r < 4; r++) invr[r] = 1.0f / lsum[r];
        ushort* ob = O + (size_t)(b * S_LEN + q0 + lg * 4) * HID + h * 64 + l15;
#pragma unroll
        for (int dt = 0; dt < 4; dt++)
#pragma unroll
            for (int r = 0; r < 4; r++) {
                union { __bf16 h; ushort u; } cv{(__bf16)(ao[dt][r] * invr[r])};
                ob[(size_t)r * HID + dt * 16] = cv.u;
            }
    }
}

// ---------------- launch ----------------
extern "C" void kernel_launch(void* const* d_in, const int* in_sizes, int n_in,
                              void* d_out, int out_size, void* d_ws, size_t ws_size,
                              hipStream_t stream) {
    const float* hidden = (const float*)d_in[0];
    const float* Wq = (const float*)d_in[1];
    const float* Wk = (const float*)d_in[2];
    const float* Wv = (const float*)d_in[3];
    const float* Wo = (const float*)d_in[4];

    char* ws = (char*)d_ws;
    size_t off = 0;
    auto alloc = [&](size_t bytes) -> void* {
        void* p = ws + off;
        off += (bytes + 255) & ~(size_t)255;
        return p;
    };
    ushort* hb   = (ushort*)alloc((size_t)NTOK * HID * 2);
    ushort* wqkv = (ushort*)alloc((size_t)NQKV * 2048 * 2);
    ushort* wo   = (ushort*)alloc((size_t)2048 * 2048 * 2);
    ushort* Qb   = (ushort*)alloc((size_t)NTOK * 2048 * 2);
    ushort* Kb   = (ushort*)alloc((size_t)NTOK * 512 * 2);
    ushort* Vb   = (ushort*)alloc((size_t)NTOK * 512 * 2);
    ushort* Vtb  = (ushort*)alloc((size_t)NTOK * 512 * 2);
    ushort* AO   = (ushort*)alloc((size_t)NTOK * 2048 * 2);

    cvt_all<<<18432, 256, 0, stream>>>(hidden, Wq, Wk, Wv, Wo, hb, wqkv, wo);

    gemm_bt<0, 1><<<dim3(24, 32), 256, 0, stream>>>(hb, wqkv, Qb, Kb, Vb, NTOK, NQKV, 2048);

    transpose_v<<<dim3(S_LEN / 32, 2, BATCH * NKV), 256, 0, stream>>>(Vb, Vtb);

    attn_k<<<dim3(16, BATCH * NH), 256, 0, stream>>>(Qb, Kb, Vtb, AO);

    gemm_bt<1, 0><<<dim3(16, 32), 256, 0, stream>>>(AO, wo, d_out, nullptr, nullptr, NTOK, 2048, 2048);
}

// Round 10
// 186.047 us; speedup vs baseline: 2.3340x; 1.1029x over previous
//
#include <hip/hip_runtime.h>

#define S_LEN 2048
#define BATCH 2
#define NH 32
#define NKV 8
#define HD 64
#define HID 2048
#define NTOK (BATCH * S_LEN)   // 4096
#define NQKV 3072              // 2048 Q + 512 K + 512 V
#define SC_Q 0.18033688011112042f   // 0.125 * log2(e)

typedef __attribute__((ext_vector_type(8))) __bf16 bf16x8;
typedef __attribute__((ext_vector_type(4))) float f32x4;

__device__ inline ushort f2b(float f) {
    union { float f; unsigned u; } x{f};
    unsigned r = (x.u + 0x7fff + ((x.u >> 16) & 1)) >> 16;
    return (ushort)r;
}
__device__ inline float ex2(float x) { return __builtin_amdgcn_exp2f(x); }  // raw v_exp_f32

// ---------------- fused fp32 -> bf16 conversion (all 5 inputs, 1 launch) ----------------
__global__ __launch_bounds__(256) void cvt_all(const float* __restrict__ hidden,
                                               const float* __restrict__ Wq,
                                               const float* __restrict__ Wk,
                                               const float* __restrict__ Wv,
                                               const float* __restrict__ Wo,
                                               ushort* __restrict__ hb,
                                               ushort* __restrict__ wqkv,
                                               ushort* __restrict__ wo) {
    int bid = blockIdx.x;
    const float* src;
    ushort* dst;
    int off;
    if (bid < 8192)        { src = hidden; dst = hb;                              off = bid; }
    else if (bid < 12288)  { src = Wq;     dst = wqkv;                            off = bid - 8192; }
    else if (bid < 13312)  { src = Wk;     dst = wqkv + (size_t)2048 * 2048;      off = bid - 12288; }
    else if (bid < 14336)  { src = Wv;     dst = wqkv + (size_t)2560 * 2048;      off = bid - 13312; }
    else                   { src = Wo;     dst = wo;                              off = bid - 14336; }
    size_t i = (size_t)off * 256 + threadIdx.x;
    float4 v = reinterpret_cast<const float4*>(src)[i];
    ushort4 o;
    o.x = f2b(v.x); o.y = f2b(v.y); o.z = f2b(v.z); o.w = f2b(v.w);
    reinterpret_cast<ushort4*>(dst)[i] = o;
}

// ---------------- global -> LDS async helper ----------------
__device__ inline void gl_lds16(const void* g, void* l) {
    __builtin_amdgcn_global_load_lds((const __attribute__((address_space(1))) void*)g,
                                     (__attribute__((address_space(3))) void*)l, 16, 0, 0);
}

// ---------------- GEMM: C[m][n] = sum_k A[m][k] * B[n][k] ----------------
// BK=64, LDS rows XOR-swizzled (f(row) = (row&7)*16 bytes) via pre-swizzled
// global source (gload_lds writes linearly). XCD-aware block swizzle.
// ROPE=1: rope+scale Q/K in-register; route head blocks to compact buffers.
template<int WF32, int ROPE>
__global__ __launch_bounds__(256) void gemm_bt(const ushort* __restrict__ A,
                                               const ushort* __restrict__ B,
                                               void* __restrict__ C,
                                               ushort* __restrict__ Kd,
                                               ushort* __restrict__ Vd,
                                               int M, int N, int K) {
    __shared__ __align__(16) ushort As[128 * 64];   // 16 KB
    __shared__ __align__(16) ushort Bs[128 * 64];   // 16 KB
    const int tid = threadIdx.x, lane = tid & 63, w = tid >> 6;
    const int wr = w >> 1, wc = w & 1, l15 = lane & 15, lg = lane >> 4;

    const int nbx = gridDim.x;
    int lid = blockIdx.y * nbx + blockIdx.x;
    const int cpx = (nbx * gridDim.y) >> 3;
    int swz = (lid & 7) * cpx + (lid >> 3);
    const int m0 = (swz / nbx) * 128, n0 = (swz % nbx) * 128;

    // staging: op j (0..3) covers rows j*32 + w*8 + (lane>>3); lane writes 16B
    // at in-row phys (lane&7)*16; source col pre-swizzled by f(row)=(row&7)*16,
    // row&7 == lane>>3 here.
    const int lsw = ((lane & 7) ^ (lane >> 3)) * 8;   // ushort offset in row
    const ushort* Ag = A + (size_t)(m0 + w * 8 + (lane >> 3)) * K + lsw;
    const ushort* Bg = B + (size_t)(n0 + w * 8 + (lane >> 3)) * K + lsw;
    ushort* lA = As + w * 512;   // (w*8) rows * 64
    ushort* lB = Bs + w * 512;

    f32x4 acc[4][4] = {};

    for (int k0 = 0; k0 < K; k0 += 64) {
        __syncthreads();
#pragma unroll
        for (int j = 0; j < 4; j++) {
            gl_lds16(Ag + (size_t)(j * 32) * K + k0, lA + j * 2048);
            gl_lds16(Bg + (size_t)(j * 32) * K + k0, lB + j * 2048);
        }
        __syncthreads();

        const char* pa = (const char*)As + (wr * 64 + l15) * 128;
        const char* pb = (const char*)Bs + (wc * 64 + l15) * 128;
        const int sw = (l15 & 7) * 16;   // f(row), row&7 == l15&7 for all i
        bf16x8 af[2][4], bff[2][4];
#pragma unroll
        for (int i = 0; i < 4; i++)
#pragma unroll
            for (int ks = 0; ks < 2; ks++) {
                const int po = (ks * 64 + lg * 16) ^ sw;
                af[ks][i]  = *(const bf16x8*)(pa + i * 2048 + po);
                bff[ks][i] = *(const bf16x8*)(pb + i * 2048 + po);
            }
#pragma unroll
        for (int ks = 0; ks < 2; ks++)
#pragma unroll
            for (int i = 0; i < 4; i++)
#pragma unroll
                for (int j = 0; j < 4; j++)
                    acc[i][j] = __builtin_amdgcn_mfma_f32_16x16x32_bf16(af[ks][i], bff[ks][j], acc[i][j], 0, 0, 0);
    }

    const int mr = m0 + wr * 64 + lg * 4, nc = n0 + wc * 64 + l15;

    if (!ROPE) {
#pragma unroll
        for (int i = 0; i < 4; i++)
#pragma unroll
            for (int j = 0; j < 4; j++)
#pragma unroll
                for (int r = 0; r < 4; r++) {
                    size_t row = mr + i * 16 + r, col = nc + j * 16;
                    if (WF32) ((float*)C)[row * N + col] = acc[i][j][r];
                    else      ((ushort*)C)[row * N + col] = f2b(acc[i][j][r]);
                }
        return;
    }

    // ---- ROPE epilogue: wave-uniform head block (64 cols) ----
    const int hq = (n0 + wc * 64) >> 6;    // 0..31 Q, 32..39 K, 40..47 V
    if (hq < 40) {
        const bool isQ = hq < 32;
        const float fd0 = ex2(-(float)l15 * 0.4152410118609203f);  // 10000^(-l15/32)
        const float fd1 = fd0 * 0.01f;                             // l15+16
#pragma unroll
        for (int i = 0; i < 4; i++)
#pragma unroll
            for (int r = 0; r < 4; r++) {
                float pos = (float)((mr + i * 16 + r) & (S_LEN - 1));
#pragma unroll
                for (int jj = 0; jj < 2; jj++) {
                    float ang = pos * (jj ? fd1 : fd0);
                    float sv, cv;
                    __sincosf(ang, &sv, &cv);
                    float x1 = acc[i][jj][r], x2 = acc[i][jj + 2][r];
                    float y0 = x1 * cv - x2 * sv;
                    float y1 = x2 * cv + x1 * sv;
                    if (isQ) { y0 *= SC_Q; y1 *= SC_Q; }
                    acc[i][jj][r] = y0;
                    acc[i][jj + 2][r] = y1;
                }
            }
    }
    ushort* dst;
    int dstride, colb;
    if (hq < 32)      { dst = (ushort*)C; dstride = 2048; colb = nc; }
    else if (hq < 40) { dst = Kd;         dstride = 512;  colb = nc - 2048; }
    else              { dst = Vd;         dstride = 512;  colb = nc - 2560; }
#pragma unroll
    for (int i = 0; i < 4; i++)
#pragma unroll
        for (int j = 0; j < 4; j++)
#pragma unroll
            for (int r = 0; r < 4; r++) {
                size_t row = mr + i * 16 + r;
                dst[row * dstride + colb + j * 16] = f2b(acc[i][j][r]);
            }
}

// ---------------- V transpose: Vb [NTOK][512] -> Vt [b][kvh][64][S] ----------------
__global__ __launch_bounds__(256) void transpose_v(const ushort* __restrict__ V,
                                                   ushort* __restrict__ Vt) {
    __shared__ ushort tile[32][33];
    int bz = blockIdx.z, b = bz >> 3, kvh = bz & 7;
    int s0 = blockIdx.x * 32, d0 = blockIdx.y * 32;
    int tx = threadIdx.x & 31, ty = threadIdx.x >> 5;
#pragma unroll
    for (int i = 0; i < 4; i++)
        tile[ty + i * 8][tx] = V[(size_t)(b * S_LEN + s0 + ty + i * 8) * 512 + kvh * 64 + d0 + tx];
    __syncthreads();
#pragma unroll
    for (int i = 0; i < 4; i++)
        Vt[((size_t)((b * 8 + kvh) * 64 + d0 + ty + i * 8)) * S_LEN + s0 + tx] = tile[tx][ty + i * 8];
}

// ---------------- Flash attention (causal, GQA) ----------------
// No online max (log2-domain scores bounded << 127); row sums via MFMA-ones.
// K/V LDS-staged, dbuf, swizzled. XCD-aware block swizzle.
__global__ __launch_bounds__(256) void attn_k(const ushort* __restrict__ Q,   // stride 2048
                                              const ushort* __restrict__ Kc,  // stride 512
                                              const ushort* __restrict__ Vt,
                                              ushort* __restrict__ O) {
    __shared__ __align__(16) ushort K_lds[2][4096];
    __shared__ __align__(16) ushort V_lds[2][4096];
    const int lane = threadIdx.x & 63, w = threadIdx.x >> 6;
    const int l15 = lane & 15, lg = lane >> 4;

    int lid = blockIdx.y * 16 + blockIdx.x;
    int swz = (lid & 7) * 128 + (lid >> 3);
    const int bxs = swz & 15;
    const int bh = swz >> 4;
    const int b = bh >> 5, h = bh & 31, kvh = h >> 2;

    const ushort* kSrc[2];
    const ushort* vSrc[2];
    int dstU[2];
#pragma unroll
    for (int j = 0; j < 2; j++) {
        int u = w * 2 + j;
        int row = u * 8 + (lane >> 3);
        int po = (lane & 7) * 16;
        int fr = ((row & 3) | (((row >> 3) & 1) << 2)) << 4;
        int dus = (po ^ fr) >> 1;
        kSrc[j] = Kc + (size_t)(b * S_LEN + row) * 512 + kvh * 64 + dus;
        vSrc[j] = Vt + ((size_t)((b * 8 + kvh) * 64 + row)) * S_LEN + dus;
        dstU[j] = u * 512;
    }

    int fr_k = ((l15 & 3) | (((l15 >> 2) & 1) << 2)) << 4;
    int kbase = 1024 * (l15 >> 2) + 128 * (l15 & 3) + ((lg * 16) ^ (fr_k & 48));
    int k6 = (fr_k >> 6) & 1;
    int kb0 = kbase + 64 * k6, kb1 = kbase + 64 * (1 - k6);
    int fr_v = ((l15 & 3) | (((l15 >> 3) & 1) << 2)) << 4;
    int vbase = 128 * l15 + ((lg * 16) ^ (fr_v & 48));
    int v6 = (fr_v >> 6) & 1;
    int vb0 = vbase + 64 * v6, vb1 = vbase + 64 * (1 - v6);

    bf16x8 onesf;
#pragma unroll
    for (int i = 0; i < 8; i++) onesf[i] = (__bf16)1.0f;

    for (int half = 0; half < 2; ++half) {
        const int bx = half ? (31 - bxs) : bxs;
        const int q0 = bx * 64 + w * 16;
        const int qrow = q0 + l15;
        const int ktend = bx;

        const ushort* qp = Q + (size_t)(b * S_LEN + qrow) * HID + h * 64 + lg * 8;
        bf16x8 qf0 = *(const bf16x8*)qp;
        bf16x8 qf1 = *(const bf16x8*)(qp + 32);

        f32x4 ao[4] = {};
        f32x4 lsum = {};

#pragma unroll
        for (int j = 0; j < 2; j++) {
            gl_lds16(kSrc[j], &K_lds[0][dstU[j]]);
            gl_lds16(vSrc[j], &V_lds[0][dstU[j]]);
        }
        __syncthreads();
        int cur = 0;

        for (int kt = 0; kt <= ktend; ++kt) {
            const int kn = kt << 6;
            if (kt < ktend) {
                const int kn2 = kn + 64;
#pragma unroll
                for (int j = 0; j < 2; j++) {
                    gl_lds16(kSrc[j] + (size_t)kn2 * 512, &K_lds[cur ^ 1][dstU[j]]);
                    gl_lds16(vSrc[j] + kn2, &V_lds[cur ^ 1][dstU[j]]);
                }
            }

            const char* Kt = (const char*)K_lds[cur];
            const char* Vl = (const char*)V_lds[cur];

            bf16x8 kf0[4], kf1[4];
#pragma unroll
            for (int kc = 0; kc < 4; kc++) {
                const int kcst = 4096 * (kc >> 1) + 512 * (kc & 1);
                kf0[kc] = *(const bf16x8*)(Kt + kb0 + kcst);
                kf1[kc] = *(const bf16x8*)(Kt + kb1 + kcst);
            }

            f32x4 s[4];
#pragma unroll
            for (int kc = 0; kc < 4; kc++) {
                f32x4 z = {};
                z = __builtin_amdgcn_mfma_f32_16x16x32_bf16(kf0[kc], qf0, z, 0, 0, 0);
                z = __builtin_amdgcn_mfma_f32_16x16x32_bf16(kf1[kc], qf1, z, 0, 0, 0);
                s[kc] = z;
            }

            if (kt == ktend) {
#pragma unroll
                for (int kc = 0; kc < 4; kc++)
#pragma unroll
                    for (int r = 0; r < 4; r++) {
                        int kv = kn + ((kc >> 1) << 5) + (lg << 3) + ((kc & 1) << 2) + r;
                        s[kc][r] = (kv <= qrow) ? s[kc][r] : -INFINITY;
                    }
            }

            bf16x8 pf0, pf1;
#pragma unroll
            for (int r = 0; r < 4; r++) {
                pf0[r]     = (__bf16)ex2(s[0][r]);
                pf0[4 + r] = (__bf16)ex2(s[1][r]);
                pf1[r]     = (__bf16)ex2(s[2][r]);
                pf1[4 + r] = (__bf16)ex2(s[3][r]);
            }

            lsum = __builtin_amdgcn_mfma_f32_16x16x32_bf16(pf0, onesf, lsum, 0, 0, 0);
            lsum = __builtin_amdgcn_mfma_f32_16x16x32_bf16(pf1, onesf, lsum, 0, 0, 0);

#pragma unroll
            for (int dt = 0; dt < 4; dt++) {
                bf16x8 vf0 = *(const bf16x8*)(Vl + vb0 + dt * 2048);
                bf16x8 vf1 = *(const bf16x8*)(Vl + vb1 + dt * 2048);
                ao[dt] = __builtin_amdgcn_mfma_f32_16x16x32_bf16(pf0, vf0, ao[dt], 0, 0, 0);
                ao[dt] = __builtin_amdgcn_mfma_f32_16x16x32_bf16(pf1, vf1, ao[dt], 0, 0, 0);
            }

            __syncthreads();
            cur ^= 1;
        }

        float invr[4];
#pragma unroll
        for (int r = 0; r < 4; r++) invr[r] = 1.0f / lsum[r];
        ushort* ob = O + (size_t)(b * S_LEN + q0 + lg * 4) * HID + h * 64 + l15;
#pragma unroll
        for (int dt = 0; dt < 4; dt++)
#pragma unroll
            for (int r = 0; r < 4; r++) {
                union { __bf16 h; ushort u; } cv{(__bf16)(ao[dt][r] * invr[r])};
                ob[(size_t)r * HID + dt * 16] = cv.u;
            }
    }
}

// ---------------- launch ----------------
extern "C" void kernel_launch(void* const* d_in, const int* in_sizes, int n_in,
                              void* d_out, int out_size, void* d_ws, size_t ws_size,
                              hipStream_t stream) {
    const float* hidden = (const float*)d_in[0];
    const float* Wq = (const float*)d_in[1];
    const float* Wk = (const float*)d_in[2];
    const float* Wv = (const float*)d_in[3];
    const float* Wo = (const float*)d_in[4];

    char* ws = (char*)d_ws;
    size_t off = 0;
    auto alloc = [&](size_t bytes) -> void* {
        void* p = ws + off;
        off += (bytes + 255) & ~(size_t)255;
        return p;
    };
    ushort* hb   = (ushort*)alloc((size_t)NTOK * HID * 2);
    ushort* wqkv = (ushort*)alloc((size_t)NQKV * 2048 * 2);
    ushort* wo   = (ushort*)alloc((size_t)2048 * 2048 * 2);
    ushort* Qb   = (ushort*)alloc((size_t)NTOK * 2048 * 2);
    ushort* Kb   = (ushort*)alloc((size_t)NTOK * 512 * 2);
    ushort* Vb   = (ushort*)alloc((size_t)NTOK * 512 * 2);
    ushort* Vtb  = (ushort*)alloc((size_t)NTOK * 512 * 2);
    ushort* AO   = (ushort*)alloc((size_t)NTOK * 2048 * 2);

    cvt_all<<<18432, 256, 0, stream>>>(hidden, Wq, Wk, Wv, Wo, hb, wqkv, wo);

    gemm_bt<0, 1><<<dim3(24, 32), 256, 0, stream>>>(hb, wqkv, Qb, Kb, Vb, NTOK, NQKV, 2048);

    transpose_v<<<dim3(S_LEN / 32, 2, BATCH * NKV), 256, 0, stream>>>(Vb, Vtb);

    attn_k<<<dim3(16, BATCH * NH), 256, 0, stream>>>(Qb, Kb, Vtb, AO);

    gemm_bt<1, 0><<<dim3(16, 32), 256, 0, stream>>>(AO, wo, d_out, nullptr, nullptr, NTOK, 2048, 2048);
}

// Round 11
// 185.436 us; speedup vs baseline: 2.3417x; 1.0033x over previous
//
#include <hip/hip_runtime.h>

#define S_LEN 2048
#define BATCH 2
#define NH 32
#define NKV 8
#define HD 64
#define HID 2048
#define NTOK (BATCH * S_LEN)   // 4096
#define NQKV 3072              // 2048 Q + 512 K + 512 V
#define SC_Q 0.18033688011112042f   // 0.125 * log2(e)

typedef __attribute__((ext_vector_type(8))) __bf16 bf16x8;
typedef __attribute__((ext_vector_type(4))) float f32x4;

__device__ inline ushort f2b(float f) {
    union { float f; unsigned u; } x{f};
    unsigned r = (x.u + 0x7fff + ((x.u >> 16) & 1)) >> 16;
    return (ushort)r;
}
__device__ inline float ex2(float x) { return __builtin_amdgcn_exp2f(x); }  // raw v_exp_f32

// ---------------- fused fp32 -> bf16 conversion (all 5 inputs, 1 launch) ----------------
__global__ __launch_bounds__(256) void cvt_all(const float* __restrict__ hidden,
                                               const float* __restrict__ Wq,
                                               const float* __restrict__ Wk,
                                               const float* __restrict__ Wv,
                                               const float* __restrict__ Wo,
                                               ushort* __restrict__ hb,
                                               ushort* __restrict__ wqkv,
                                               ushort* __restrict__ wo) {
    int bid = blockIdx.x;
    const float* src;
    ushort* dst;
    int off;
    if (bid < 8192)        { src = hidden; dst = hb;                              off = bid; }
    else if (bid < 12288)  { src = Wq;     dst = wqkv;                            off = bid - 8192; }
    else if (bid < 13312)  { src = Wk;     dst = wqkv + (size_t)2048 * 2048;      off = bid - 12288; }
    else if (bid < 14336)  { src = Wv;     dst = wqkv + (size_t)2560 * 2048;      off = bid - 13312; }
    else                   { src = Wo;     dst = wo;                              off = bid - 14336; }
    size_t i = (size_t)off * 256 + threadIdx.x;
    float4 v = reinterpret_cast<const float4*>(src)[i];
    ushort4 o;
    o.x = f2b(v.x); o.y = f2b(v.y); o.z = f2b(v.z); o.w = f2b(v.w);
    reinterpret_cast<ushort4*>(dst)[i] = o;
}

// ---------------- global -> LDS async helper ----------------
__device__ inline void gl_lds16(const void* g, void* l) {
    __builtin_amdgcn_global_load_lds((const __attribute__((address_space(1))) void*)g,
                                     (__attribute__((address_space(3))) void*)l, 16, 0, 0);
}

// ---------------- GEMM: C[m][n] = sum_k A[m][k] * B[n][k] ----------------
// BK=64, LDS rows XOR-swizzled (f(row) = (row&7)*16 bytes) via pre-swizzled
// global source (gload_lds writes linearly). XCD-aware block swizzle.
// ROPE=1: rope+scale Q/K in-register; route head blocks to compact buffers.
template<int WF32, int ROPE>
__global__ __launch_bounds__(256) void gemm_bt(const ushort* __restrict__ A,
                                               const ushort* __restrict__ B,
                                               void* __restrict__ C,
                                               ushort* __restrict__ Kd,
                                               ushort* __restrict__ Vd,
                                               int M, int N, int K) {
    __shared__ __align__(16) ushort As[128 * 64];   // 16 KB
    __shared__ __align__(16) ushort Bs[128 * 64];   // 16 KB
    const int tid = threadIdx.x, lane = tid & 63, w = tid >> 6;
    const int wr = w >> 1, wc = w & 1, l15 = lane & 15, lg = lane >> 4;

    const int nbx = gridDim.x;
    int lid = blockIdx.y * nbx + blockIdx.x;
    const int cpx = (nbx * gridDim.y) >> 3;
    int swz = (lid & 7) * cpx + (lid >> 3);
    const int m0 = (swz / nbx) * 128, n0 = (swz % nbx) * 128;

    const int lsw = ((lane & 7) ^ (lane >> 3)) * 8;   // pre-swizzled source col
    const ushort* Ag = A + (size_t)(m0 + w * 8 + (lane >> 3)) * K + lsw;
    const ushort* Bg = B + (size_t)(n0 + w * 8 + (lane >> 3)) * K + lsw;
    ushort* lA = As + w * 512;
    ushort* lB = Bs + w * 512;

    f32x4 acc[4][4] = {};

    for (int k0 = 0; k0 < K; k0 += 64) {
        __syncthreads();
#pragma unroll
        for (int j = 0; j < 4; j++) {
            gl_lds16(Ag + (size_t)(j * 32) * K + k0, lA + j * 2048);
            gl_lds16(Bg + (size_t)(j * 32) * K + k0, lB + j * 2048);
        }
        __syncthreads();

        const char* pa = (const char*)As + (wr * 64 + l15) * 128;
        const char* pb = (const char*)Bs + (wc * 64 + l15) * 128;
        const int sw = (l15 & 7) * 16;
        bf16x8 af[2][4], bff[2][4];
#pragma unroll
        for (int i = 0; i < 4; i++)
#pragma unroll
            for (int ks = 0; ks < 2; ks++) {
                const int po = (ks * 64 + lg * 16) ^ sw;
                af[ks][i]  = *(const bf16x8*)(pa + i * 2048 + po);
                bff[ks][i] = *(const bf16x8*)(pb + i * 2048 + po);
            }
#pragma unroll
        for (int ks = 0; ks < 2; ks++)
#pragma unroll
            for (int i = 0; i < 4; i++)
#pragma unroll
                for (int j = 0; j < 4; j++)
                    acc[i][j] = __builtin_amdgcn_mfma_f32_16x16x32_bf16(af[ks][i], bff[ks][j], acc[i][j], 0, 0, 0);
    }

    const int mr = m0 + wr * 64 + lg * 4, nc = n0 + wc * 64 + l15;

    if (!ROPE) {
#pragma unroll
        for (int i = 0; i < 4; i++)
#pragma unroll
            for (int j = 0; j < 4; j++)
#pragma unroll
                for (int r = 0; r < 4; r++) {
                    size_t row = mr + i * 16 + r, col = nc + j * 16;
                    if (WF32) ((float*)C)[row * N + col] = acc[i][j][r];
                    else      ((ushort*)C)[row * N + col] = f2b(acc[i][j][r]);
                }
        return;
    }

    // ---- ROPE epilogue: wave-uniform head block (64 cols) ----
    const int hq = (n0 + wc * 64) >> 6;    // 0..31 Q, 32..39 K, 40..47 V
    if (hq < 40) {
        const bool isQ = hq < 32;
        const float fd0 = ex2(-(float)l15 * 0.4152410118609203f);  // 10000^(-l15/32)
        const float fd1 = fd0 * 0.01f;                             // l15+16
#pragma unroll
        for (int i = 0; i < 4; i++)
#pragma unroll
            for (int r = 0; r < 4; r++) {
                float pos = (float)((mr + i * 16 + r) & (S_LEN - 1));
#pragma unroll
                for (int jj = 0; jj < 2; jj++) {
                    float ang = pos * (jj ? fd1 : fd0);
                    float sv, cv;
                    __sincosf(ang, &sv, &cv);
                    float x1 = acc[i][jj][r], x2 = acc[i][jj + 2][r];
                    float y0 = x1 * cv - x2 * sv;
                    float y1 = x2 * cv + x1 * sv;
                    if (isQ) { y0 *= SC_Q; y1 *= SC_Q; }
                    acc[i][jj][r] = y0;
                    acc[i][jj + 2][r] = y1;
                }
            }
    }
    ushort* dst;
    int dstride, colb;
    if (hq < 32)      { dst = (ushort*)C; dstride = 2048; colb = nc; }
    else if (hq < 40) { dst = Kd;         dstride = 512;  colb = nc - 2048; }
    else              { dst = Vd;         dstride = 512;  colb = nc - 2560; }
#pragma unroll
    for (int i = 0; i < 4; i++)
#pragma unroll
        for (int j = 0; j < 4; j++)
#pragma unroll
            for (int r = 0; r < 4; r++) {
                size_t row = mr + i * 16 + r;
                dst[row * dstride + colb + j * 16] = f2b(acc[i][j][r]);
            }
}

// ---------------- V transpose: Vb [NTOK][512] -> Vt [b][kvh][64][S] ----------------
__global__ __launch_bounds__(256) void transpose_v(const ushort* __restrict__ V,
                                                   ushort* __restrict__ Vt) {
    __shared__ ushort tile[32][33];
    int bz = blockIdx.z, b = bz >> 3, kvh = bz & 7;
    int s0 = blockIdx.x * 32, d0 = blockIdx.y * 32;
    int tx = threadIdx.x & 31, ty = threadIdx.x >> 5;
#pragma unroll
    for (int i = 0; i < 4; i++)
        tile[ty + i * 8][tx] = V[(size_t)(b * S_LEN + s0 + ty + i * 8) * 512 + kvh * 64 + d0 + tx];
    __syncthreads();
#pragma unroll
    for (int i = 0; i < 4; i++)
        Vt[((size_t)((b * 8 + kvh) * 64 + d0 + ty + i * 8)) * S_LEN + s0 + tx] = tile[tx][ty + i * 8];
}

// ---------------- Flash attention (causal, GQA) ----------------
// MERGED halves: block handles q-tiles A=bx and B=31-bx in ONE kv loop.
// kt = 0..31-bx; both tiles consume the same LDS K/V tile while kt <= bx.
// Barriers+staging drop 33 -> 32-bx per block (avg -26%); compute uniform.
// No online max (log2-domain scores bounded); row sums via MFMA-ones.
__global__ __launch_bounds__(256) void attn_k(const ushort* __restrict__ Q,   // stride 2048
                                              const ushort* __restrict__ Kc,  // stride 512
                                              const ushort* __restrict__ Vt,
                                              ushort* __restrict__ O) {
    __shared__ __align__(16) ushort K_lds[2][4096];
    __shared__ __align__(16) ushort V_lds[2][4096];
    const int lane = threadIdx.x & 63, w = threadIdx.x >> 6;
    const int l15 = lane & 15, lg = lane >> 4;

    int lid = blockIdx.y * 16 + blockIdx.x;
    int swz = (lid & 7) * 128 + (lid >> 3);
    const int bxs = swz & 15;
    const int bh = swz >> 4;
    const int b = bh >> 5, h = bh & 31, kvh = h >> 2;

    const ushort* kSrc[2];
    const ushort* vSrc[2];
    int dstU[2];
#pragma unroll
    for (int j = 0; j < 2; j++) {
        int u = w * 2 + j;
        int row = u * 8 + (lane >> 3);
        int po = (lane & 7) * 16;
        int fr = ((row & 3) | (((row >> 3) & 1) << 2)) << 4;
        int dus = (po ^ fr) >> 1;
        kSrc[j] = Kc + (size_t)(b * S_LEN + row) * 512 + kvh * 64 + dus;
        vSrc[j] = Vt + ((size_t)((b * 8 + kvh) * 64 + row)) * S_LEN + dus;
        dstU[j] = u * 512;
    }

    int fr_k = ((l15 & 3) | (((l15 >> 2) & 1) << 2)) << 4;
    int kbase = 1024 * (l15 >> 2) + 128 * (l15 & 3) + ((lg * 16) ^ (fr_k & 48));
    int k6 = (fr_k >> 6) & 1;
    int kb0 = kbase + 64 * k6, kb1 = kbase + 64 * (1 - k6);
    int fr_v = ((l15 & 3) | (((l15 >> 3) & 1) << 2)) << 4;
    int vbase = 128 * l15 + ((lg * 16) ^ (fr_v & 48));
    int v6 = (fr_v >> 6) & 1;
    int vb0 = vbase + 64 * v6, vb1 = vbase + 64 * (1 - v6);

    bf16x8 onesf;
#pragma unroll
    for (int i = 0; i < 8; i++) onesf[i] = (__bf16)1.0f;

    // two q-tiles: A = bxs (short), B = 31-bxs (long)
    const int ktA = bxs, ktB = 31 - bxs;
    const int q0A = bxs * 64 + w * 16, q0B = (31 - bxs) * 64 + w * 16;
    const int qrowA = q0A + l15, qrowB = q0B + l15;

    const ushort* qpA = Q + (size_t)(b * S_LEN + qrowA) * HID + h * 64 + lg * 8;
    const ushort* qpB = Q + (size_t)(b * S_LEN + qrowB) * HID + h * 64 + lg * 8;
    bf16x8 qfA0 = *(const bf16x8*)qpA, qfA1 = *(const bf16x8*)(qpA + 32);
    bf16x8 qfB0 = *(const bf16x8*)qpB, qfB1 = *(const bf16x8*)(qpB + 32);

    f32x4 aoA[4] = {}, aoB[4] = {};
    f32x4 lsumA = {}, lsumB = {};

#pragma unroll
    for (int j = 0; j < 2; j++) {
        gl_lds16(kSrc[j], &K_lds[0][dstU[j]]);
        gl_lds16(vSrc[j], &V_lds[0][dstU[j]]);
    }
    __syncthreads();
    int cur = 0;

    for (int kt = 0; kt <= ktB; ++kt) {
        const int kn = kt << 6;
        if (kt < ktB) {
            const int kn2 = kn + 64;
#pragma unroll
            for (int j = 0; j < 2; j++) {
                gl_lds16(kSrc[j] + (size_t)kn2 * 512, &K_lds[cur ^ 1][dstU[j]]);
                gl_lds16(vSrc[j] + kn2, &V_lds[cur ^ 1][dstU[j]]);
            }
        }

        const char* Kt = (const char*)K_lds[cur];
        const char* Vl = (const char*)V_lds[cur];
        const bool aAct = (kt <= ktA);

        bf16x8 kf0[4], kf1[4];
#pragma unroll
        for (int kc = 0; kc < 4; kc++) {
            const int kcst = 4096 * (kc >> 1) + 512 * (kc & 1);
            kf0[kc] = *(const bf16x8*)(Kt + kb0 + kcst);
            kf1[kc] = *(const bf16x8*)(Kt + kb1 + kcst);
        }

        // ---- QK^T for B (always) and A (while active) ----
        f32x4 sB[4], sA[4];
#pragma unroll
        for (int kc = 0; kc < 4; kc++) {
            f32x4 z = {};
            z = __builtin_amdgcn_mfma_f32_16x16x32_bf16(kf0[kc], qfB0, z, 0, 0, 0);
            z = __builtin_amdgcn_mfma_f32_16x16x32_bf16(kf1[kc], qfB1, z, 0, 0, 0);
            sB[kc] = z;
        }
        if (aAct) {
#pragma unroll
            for (int kc = 0; kc < 4; kc++) {
                f32x4 z = {};
                z = __builtin_amdgcn_mfma_f32_16x16x32_bf16(kf0[kc], qfA0, z, 0, 0, 0);
                z = __builtin_amdgcn_mfma_f32_16x16x32_bf16(kf1[kc], qfA1, z, 0, 0, 0);
                sA[kc] = z;
            }
        }

        // ---- diagonal masks ----
        if (kt == ktB) {
#pragma unroll
            for (int kc = 0; kc < 4; kc++)
#pragma unroll
                for (int r = 0; r < 4; r++) {
                    int kv = kn + ((kc >> 1) << 5) + (lg << 3) + ((kc & 1) << 2) + r;
                    sB[kc][r] = (kv <= qrowB) ? sB[kc][r] : -INFINITY;
                }
        }
        if (kt == ktA) {
#pragma unroll
            for (int kc = 0; kc < 4; kc++)
#pragma unroll
                for (int r = 0; r < 4; r++) {
                    int kv = kn + ((kc >> 1) << 5) + (lg << 3) + ((kc & 1) << 2) + r;
                    sA[kc][r] = (kv <= qrowA) ? sA[kc][r] : -INFINITY;
                }
        }

        // ---- p = exp2(s), pack, row-sum via MFMA-ones, PV ----
        bf16x8 pB0, pB1, pA0, pA1;
#pragma unroll
        for (int r = 0; r < 4; r++) {
            pB0[r]     = (__bf16)ex2(sB[0][r]);
            pB0[4 + r] = (__bf16)ex2(sB[1][r]);
            pB1[r]     = (__bf16)ex2(sB[2][r]);
            pB1[4 + r] = (__bf16)ex2(sB[3][r]);
        }
        if (aAct) {
#pragma unroll
            for (int r = 0; r < 4; r++) {
                pA0[r]     = (__bf16)ex2(sA[0][r]);
                pA0[4 + r] = (__bf16)ex2(sA[1][r]);
                pA1[r]     = (__bf16)ex2(sA[2][r]);
                pA1[4 + r] = (__bf16)ex2(sA[3][r]);
            }
        }

        lsumB = __builtin_amdgcn_mfma_f32_16x16x32_bf16(pB0, onesf, lsumB, 0, 0, 0);
        lsumB = __builtin_amdgcn_mfma_f32_16x16x32_bf16(pB1, onesf, lsumB, 0, 0, 0);
        if (aAct) {
            lsumA = __builtin_amdgcn_mfma_f32_16x16x32_bf16(pA0, onesf, lsumA, 0, 0, 0);
            lsumA = __builtin_amdgcn_mfma_f32_16x16x32_bf16(pA1, onesf, lsumA, 0, 0, 0);
        }

#pragma unroll
        for (int dt = 0; dt < 4; dt++) {
            bf16x8 vf0 = *(const bf16x8*)(Vl + vb0 + dt * 2048);
            bf16x8 vf1 = *(const bf16x8*)(Vl + vb1 + dt * 2048);
            aoB[dt] = __builtin_amdgcn_mfma_f32_16x16x32_bf16(pB0, vf0, aoB[dt], 0, 0, 0);
            aoB[dt] = __builtin_amdgcn_mfma_f32_16x16x32_bf16(pB1, vf1, aoB[dt], 0, 0, 0);
            if (aAct) {
                aoA[dt] = __builtin_amdgcn_mfma_f32_16x16x32_bf16(pA0, vf0, aoA[dt], 0, 0, 0);
                aoA[dt] = __builtin_amdgcn_mfma_f32_16x16x32_bf16(pA1, vf1, aoA[dt], 0, 0, 0);
            }
        }

        __syncthreads();
        cur ^= 1;
    }

    // ---- epilogue: both tiles ----
    float invA[4], invB[4];
#pragma unroll
    for (int r = 0; r < 4; r++) { invA[r] = 1.0f / lsumA[r]; invB[r] = 1.0f / lsumB[r]; }
    ushort* obA = O + (size_t)(b * S_LEN + q0A + lg * 4) * HID + h * 64 + l15;
    ushort* obB = O + (size_t)(b * S_LEN + q0B + lg * 4) * HID + h * 64 + l15;
#pragma unroll
    for (int dt = 0; dt < 4; dt++)
#pragma unroll
        for (int r = 0; r < 4; r++) {
            union { __bf16 h; ushort u; } cA{(__bf16)(aoA[dt][r] * invA[r])};
            union { __bf16 h; ushort u; } cB{(__bf16)(aoB[dt][r] * invB[r])};
            obA[(size_t)r * HID + dt * 16] = cA.u;
            obB[(size_t)r * HID + dt * 16] = cB.u;
        }
}

// ---------------- launch ----------------
extern "C" void kernel_launch(void* const* d_in, const int* in_sizes, int n_in,
                              void* d_out, int out_size, void* d_ws, size_t ws_size,
                              hipStream_t stream) {
    const float* hidden = (const float*)d_in[0];
    const float* Wq = (const float*)d_in[1];
    const float* Wk = (const float*)d_in[2];
    const float* Wv = (const float*)d_in[3];
    const float* Wo = (const float*)d_in[4];

    char* ws = (char*)d_ws;
    size_t off = 0;
    auto alloc = [&](size_t bytes) -> void* {
        void* p = ws + off;
        off += (bytes + 255) & ~(size_t)255;
        return p;
    };
    ushort* hb   = (ushort*)alloc((size_t)NTOK * HID * 2);
    ushort* wqkv = (ushort*)alloc((size_t)NQKV * 2048 * 2);
    ushort* wo   = (ushort*)alloc((size_t)2048 * 2048 * 2);
    ushort* Qb   = (ushort*)alloc((size_t)NTOK * 2048 * 2);
    ushort* Kb   = (ushort*)alloc((size_t)NTOK * 512 * 2);
    ushort* Vb   = (ushort*)alloc((size_t)NTOK * 512 * 2);
    ushort* Vtb  = (ushort*)alloc((size_t)NTOK * 512 * 2);
    ushort* AO   = (ushort*)alloc((size_t)NTOK * 2048 * 2);

    cvt_all<<<18432, 256, 0, stream>>>(hidden, Wq, Wk, Wv, Wo, hb, wqkv, wo);

    gemm_bt<0, 1><<<dim3(24, 32), 256, 0, stream>>>(hb, wqkv, Qb, Kb, Vb, NTOK, NQKV, 2048);

    transpose_v<<<dim3(S_LEN / 32, 2, BATCH * NKV), 256, 0, stream>>>(Vb, Vtb);

    attn_k<<<dim3(16, BATCH * NH), 256, 0, stream>>>(Qb, Kb, Vtb, AO);

    gemm_bt<1, 0><<<dim3(16, 32), 256, 0, stream>>>(AO, wo, d_out, nullptr, nullptr, NTOK, 2048, 2048);
}

// Round 12
// 183.315 us; speedup vs baseline: 2.3688x; 1.0116x over previous
//
#include <hip/hip_runtime.h>

#define S_LEN 2048
#define BATCH 2
#define NH 32
#define NKV 8
#define HD 64
#define HID 2048
#define NTOK (BATCH * S_LEN)   // 4096
#define NQKV 3072              // 2048 Q + 512 K + 512 V
#define SC_Q 0.18033688011112042f   // 0.125 * log2(e)

typedef __attribute__((ext_vector_type(8))) __bf16 bf16x8;
typedef __attribute__((ext_vector_type(4))) float f32x4;

__device__ inline ushort f2b(float f) {
    union { float f; unsigned u; } x{f};
    unsigned r = (x.u + 0x7fff + ((x.u >> 16) & 1)) >> 16;
    return (ushort)r;
}
__device__ inline float ex2(float x) { return __builtin_amdgcn_exp2f(x); }  // raw v_exp_f32

// ---------------- fused fp32 -> bf16 conversion (all 5 inputs, 1 launch) ----------------
__global__ __launch_bounds__(256) void cvt_all(const float* __restrict__ hidden,
                                               const float* __restrict__ Wq,
                                               const float* __restrict__ Wk,
                                               const float* __restrict__ Wv,
                                               const float* __restrict__ Wo,
                                               ushort* __restrict__ hb,
                                               ushort* __restrict__ wqkv,
                                               ushort* __restrict__ wo) {
    int bid = blockIdx.x;
    const float* src;
    ushort* dst;
    int off;
    if (bid < 8192)        { src = hidden; dst = hb;                              off = bid; }
    else if (bid < 12288)  { src = Wq;     dst = wqkv;                            off = bid - 8192; }
    else if (bid < 13312)  { src = Wk;     dst = wqkv + (size_t)2048 * 2048;      off = bid - 12288; }
    else if (bid < 14336)  { src = Wv;     dst = wqkv + (size_t)2560 * 2048;      off = bid - 13312; }
    else                   { src = Wo;     dst = wo;                              off = bid - 14336; }
    size_t i = (size_t)off * 256 + threadIdx.x;
    float4 v = reinterpret_cast<const float4*>(src)[i];
    ushort4 o;
    o.x = f2b(v.x); o.y = f2b(v.y); o.z = f2b(v.z); o.w = f2b(v.w);
    reinterpret_cast<ushort4*>(dst)[i] = o;
}

// ---------------- global -> LDS async helper ----------------
__device__ inline void gl_lds16(const void* g, void* l) {
    __builtin_amdgcn_global_load_lds((const __attribute__((address_space(1))) void*)g,
                                     (__attribute__((address_space(3))) void*)l, 16, 0, 0);
}

// ---------------- GEMM: C[m][n] = sum_k A[m][k] * B[n][k] ----------------
// BK=64, LDS rows XOR-swizzled via pre-swizzled global source. XCD swizzle.
// ROPE=1: rope+scale Q/K in-register; route head blocks to compact buffers.
template<int WF32, int ROPE>
__global__ __launch_bounds__(256) void gemm_bt(const ushort* __restrict__ A,
                                               const ushort* __restrict__ B,
                                               void* __restrict__ C,
                                               ushort* __restrict__ Kd,
                                               ushort* __restrict__ Vd,
                                               int M, int N, int K) {
    __shared__ __align__(16) ushort As[128 * 64];   // 16 KB
    __shared__ __align__(16) ushort Bs[128 * 64];   // 16 KB
    const int tid = threadIdx.x, lane = tid & 63, w = tid >> 6;
    const int wr = w >> 1, wc = w & 1, l15 = lane & 15, lg = lane >> 4;

    const int nbx = gridDim.x;
    int lid = blockIdx.y * nbx + blockIdx.x;
    const int cpx = (nbx * gridDim.y) >> 3;
    int swz = (lid & 7) * cpx + (lid >> 3);
    const int m0 = (swz / nbx) * 128, n0 = (swz % nbx) * 128;

    const int lsw = ((lane & 7) ^ (lane >> 3)) * 8;   // pre-swizzled source col
    const ushort* Ag = A + (size_t)(m0 + w * 8 + (lane >> 3)) * K + lsw;
    const ushort* Bg = B + (size_t)(n0 + w * 8 + (lane >> 3)) * K + lsw;
    ushort* lA = As + w * 512;
    ushort* lB = Bs + w * 512;

    f32x4 acc[4][4] = {};

    for (int k0 = 0; k0 < K; k0 += 64) {
        __syncthreads();
#pragma unroll
        for (int j = 0; j < 4; j++) {
            gl_lds16(Ag + (size_t)(j * 32) * K + k0, lA + j * 2048);
            gl_lds16(Bg + (size_t)(j * 32) * K + k0, lB + j * 2048);
        }
        __syncthreads();

        const char* pa = (const char*)As + (wr * 64 + l15) * 128;
        const char* pb = (const char*)Bs + (wc * 64 + l15) * 128;
        const int sw = (l15 & 7) * 16;
        bf16x8 af[2][4], bff[2][4];
#pragma unroll
        for (int i = 0; i < 4; i++)
#pragma unroll
            for (int ks = 0; ks < 2; ks++) {
                const int po = (ks * 64 + lg * 16) ^ sw;
                af[ks][i]  = *(const bf16x8*)(pa + i * 2048 + po);
                bff[ks][i] = *(const bf16x8*)(pb + i * 2048 + po);
            }
#pragma unroll
        for (int ks = 0; ks < 2; ks++)
#pragma unroll
            for (int i = 0; i < 4; i++)
#pragma unroll
                for (int j = 0; j < 4; j++)
                    acc[i][j] = __builtin_amdgcn_mfma_f32_16x16x32_bf16(af[ks][i], bff[ks][j], acc[i][j], 0, 0, 0);
    }

    const int mr = m0 + wr * 64 + lg * 4, nc = n0 + wc * 64 + l15;

    if (!ROPE) {
#pragma unroll
        for (int i = 0; i < 4; i++)
#pragma unroll
            for (int j = 0; j < 4; j++)
#pragma unroll
                for (int r = 0; r < 4; r++) {
                    size_t row = mr + i * 16 + r, col = nc + j * 16;
                    if (WF32) ((float*)C)[row * N + col] = acc[i][j][r];
                    else      ((ushort*)C)[row * N + col] = f2b(acc[i][j][r]);
                }
        return;
    }

    // ---- ROPE epilogue: wave-uniform head block (64 cols) ----
    const int hq = (n0 + wc * 64) >> 6;    // 0..31 Q, 32..39 K, 40..47 V
    if (hq < 40) {
        const bool isQ = hq < 32;
        const float fd0 = ex2(-(float)l15 * 0.4152410118609203f);  // 10000^(-l15/32)
        const float fd1 = fd0 * 0.01f;                             // l15+16
#pragma unroll
        for (int i = 0; i < 4; i++)
#pragma unroll
            for (int r = 0; r < 4; r++) {
                float pos = (float)((mr + i * 16 + r) & (S_LEN - 1));
#pragma unroll
                for (int jj = 0; jj < 2; jj++) {
                    float ang = pos * (jj ? fd1 : fd0);
                    float sv, cv;
                    __sincosf(ang, &sv, &cv);
                    float x1 = acc[i][jj][r], x2 = acc[i][jj + 2][r];
                    float y0 = x1 * cv - x2 * sv;
                    float y1 = x2 * cv + x1 * sv;
                    if (isQ) { y0 *= SC_Q; y1 *= SC_Q; }
                    acc[i][jj][r] = y0;
                    acc[i][jj + 2][r] = y1;
                }
            }
    }
    ushort* dst;
    int dstride, colb;
    if (hq < 32)      { dst = (ushort*)C; dstride = 2048; colb = nc; }
    else if (hq < 40) { dst = Kd;         dstride = 512;  colb = nc - 2048; }
    else              { dst = Vd;         dstride = 512;  colb = nc - 2560; }
#pragma unroll
    for (int i = 0; i < 4; i++)
#pragma unroll
        for (int j = 0; j < 4; j++)
#pragma unroll
            for (int r = 0; r < 4; r++) {
                size_t row = mr + i * 16 + r;
                dst[row * dstride + colb + j * 16] = f2b(acc[i][j][r]);
            }
}

// ---------------- V transpose: Vb [NTOK][512] -> Vt [b][kvh][64][S] ----------------
__global__ __launch_bounds__(256) void transpose_v(const ushort* __restrict__ V,
                                                   ushort* __restrict__ Vt) {
    __shared__ ushort tile[32][33];
    int bz = blockIdx.z, b = bz >> 3, kvh = bz & 7;
    int s0 = blockIdx.x * 32, d0 = blockIdx.y * 32;
    int tx = threadIdx.x & 31, ty = threadIdx.x >> 5;
#pragma unroll
    for (int i = 0; i < 4; i++)
        tile[ty + i * 8][tx] = V[(size_t)(b * S_LEN + s0 + ty + i * 8) * 512 + kvh * 64 + d0 + tx];
    __syncthreads();
#pragma unroll
    for (int i = 0; i < 4; i++)
        Vt[((size_t)((b * 8 + kvh) * 64 + d0 + ty + i * 8)) * S_LEN + s0 + tx] = tile[tx][ty + i * 8];
}

// ---------------- Flash attention (causal, GQA) ----------------
// r10 balanced schedule (2 sequential halves, 33 uniform iterations/block)
// + T3/T4 counted-vmcnt pipeline: 3 LDS buffers, 2-deep prefetch, raw
// s_barrier, vmcnt(4) steady-state (never 0 mid-loop). No online max;
// row sums via MFMA-ones.
__global__ __launch_bounds__(256) void attn_k(const ushort* __restrict__ Q,   // stride 2048
                                              const ushort* __restrict__ Kc,  // stride 512
                                              const ushort* __restrict__ Vt,
                                              ushort* __restrict__ O) {
    __shared__ __align__(16) ushort K_lds[3][4096];   // 24 KB
    __shared__ __align__(16) ushort V_lds[3][4096];   // 24 KB
    const int lane = threadIdx.x & 63, w = threadIdx.x >> 6;
    const int l15 = lane & 15, lg = lane >> 4;

    int lid = blockIdx.y * 16 + blockIdx.x;
    int swz = (lid & 7) * 128 + (lid >> 3);
    const int bxs = swz & 15;
    const int bh = swz >> 4;
    const int b = bh >> 5, h = bh & 31, kvh = h >> 2;

    const ushort* kSrc[2];
    const ushort* vSrc[2];
    int dstU[2];
#pragma unroll
    for (int j = 0; j < 2; j++) {
        int u = w * 2 + j;
        int row = u * 8 + (lane >> 3);
        int po = (lane & 7) * 16;
        int fr = ((row & 3) | (((row >> 3) & 1) << 2)) << 4;
        int dus = (po ^ fr) >> 1;
        kSrc[j] = Kc + (size_t)(b * S_LEN + row) * 512 + kvh * 64 + dus;
        vSrc[j] = Vt + ((size_t)((b * 8 + kvh) * 64 + row)) * S_LEN + dus;
        dstU[j] = u * 512;
    }

    int fr_k = ((l15 & 3) | (((l15 >> 2) & 1) << 2)) << 4;
    int kbase = 1024 * (l15 >> 2) + 128 * (l15 & 3) + ((lg * 16) ^ (fr_k & 48));
    int k6 = (fr_k >> 6) & 1;
    int kb0 = kbase + 64 * k6, kb1 = kbase + 64 * (1 - k6);
    int fr_v = ((l15 & 3) | (((l15 >> 3) & 1) << 2)) << 4;
    int vbase = 128 * l15 + ((lg * 16) ^ (fr_v & 48));
    int v6 = (fr_v >> 6) & 1;
    int vb0 = vbase + 64 * v6, vb1 = vbase + 64 * (1 - v6);

    bf16x8 onesf;
#pragma unroll
    for (int i = 0; i < 8; i++) onesf[i] = (__bf16)1.0f;

    for (int half = 0; half < 2; ++half) {
        const int bx = half ? (31 - bxs) : bxs;
        const int q0 = bx * 64 + w * 16;
        const int qrow = q0 + l15;
        const int ktend = bx;

        const ushort* qp = Q + (size_t)(b * S_LEN + qrow) * HID + h * 64 + lg * 8;
        bf16x8 qf0 = *(const bf16x8*)qp;
        bf16x8 qf1 = *(const bf16x8*)(qp + 32);
        // drain Q loads (and any prior stores) so in-loop vmcnt tracks staging only
        asm volatile("s_waitcnt vmcnt(0)" ::: "memory");

        f32x4 ao[4] = {};
        f32x4 lsum = {};

        // 3-buffer pipeline: i0 = tile kt, i1 = kt+1, i2 = kt+2 staging target
        int i0 = 0, i1 = 1, i2 = 2;
        // prologue: stage tile 0 (and 1 if present), 4 gl_lds ops per stage per wave
#pragma unroll
        for (int j = 0; j < 2; j++) {
            gl_lds16(kSrc[j], &K_lds[0][dstU[j]]);
            gl_lds16(vSrc[j], &V_lds[0][dstU[j]]);
        }
        if (ktend >= 1) {
#pragma unroll
            for (int j = 0; j < 2; j++) {
                gl_lds16(kSrc[j] + (size_t)64 * 512, &K_lds[1][dstU[j]]);
                gl_lds16(vSrc[j] + 64, &V_lds[1][dstU[j]]);
            }
        }

        for (int kt = 0; kt <= ktend; ++kt) {
            const int kn = kt << 6;
            // wait for tile kt (leave tile kt+1's 4 ops in flight)
            if (kt < ktend) asm volatile("s_waitcnt vmcnt(4)" ::: "memory");
            else            asm volatile("s_waitcnt vmcnt(0)" ::: "memory");
            __builtin_amdgcn_s_barrier();   // all waves' tile-kt writes visible

            // stage tile kt+2 into the buffer all waves finished last iteration
            if (kt + 2 <= ktend) {
                const int kn2 = kn + 128;
#pragma unroll
                for (int j = 0; j < 2; j++) {
                    gl_lds16(kSrc[j] + (size_t)kn2 * 512, &K_lds[i2][dstU[j]]);
                    gl_lds16(vSrc[j] + kn2, &V_lds[i2][dstU[j]]);
                }
            }

            const char* Kt = (const char*)&K_lds[i0][0];
            const char* Vl = (const char*)&V_lds[i0][0];

            bf16x8 kf0[4], kf1[4];
#pragma unroll
            for (int kc = 0; kc < 4; kc++) {
                const int kcst = 4096 * (kc >> 1) + 512 * (kc & 1);
                kf0[kc] = *(const bf16x8*)(Kt + kb0 + kcst);
                kf1[kc] = *(const bf16x8*)(Kt + kb1 + kcst);
            }

            f32x4 s[4];
#pragma unroll
            for (int kc = 0; kc < 4; kc++) {
                f32x4 z = {};
                z = __builtin_amdgcn_mfma_f32_16x16x32_bf16(kf0[kc], qf0, z, 0, 0, 0);
                z = __builtin_amdgcn_mfma_f32_16x16x32_bf16(kf1[kc], qf1, z, 0, 0, 0);
                s[kc] = z;
            }

            if (kt == ktend) {
#pragma unroll
                for (int kc = 0; kc < 4; kc++)
#pragma unroll
                    for (int r = 0; r < 4; r++) {
                        int kv = kn + ((kc >> 1) << 5) + (lg << 3) + ((kc & 1) << 2) + r;
                        s[kc][r] = (kv <= qrow) ? s[kc][r] : -INFINITY;
                    }
            }

            bf16x8 pf0, pf1;
#pragma unroll
            for (int r = 0; r < 4; r++) {
                pf0[r]     = (__bf16)ex2(s[0][r]);
                pf0[4 + r] = (__bf16)ex2(s[1][r]);
                pf1[r]     = (__bf16)ex2(s[2][r]);
                pf1[4 + r] = (__bf16)ex2(s[3][r]);
            }

            lsum = __builtin_amdgcn_mfma_f32_16x16x32_bf16(pf0, onesf, lsum, 0, 0, 0);
            lsum = __builtin_amdgcn_mfma_f32_16x16x32_bf16(pf1, onesf, lsum, 0, 0, 0);

#pragma unroll
            for (int dt = 0; dt < 4; dt++) {
                bf16x8 vf0 = *(const bf16x8*)(Vl + vb0 + dt * 2048);
                bf16x8 vf1 = *(const bf16x8*)(Vl + vb1 + dt * 2048);
                ao[dt] = __builtin_amdgcn_mfma_f32_16x16x32_bf16(pf0, vf0, ao[dt], 0, 0, 0);
                ao[dt] = __builtin_amdgcn_mfma_f32_16x16x32_bf16(pf1, vf1, ao[dt], 0, 0, 0);
            }

            int t = i0; i0 = i1; i1 = i2; i2 = t;   // rotate buffers
        }

        float invr[4];
#pragma unroll
        for (int r = 0; r < 4; r++) invr[r] = 1.0f / lsum[r];
        ushort* ob = O + (size_t)(b * S_LEN + q0 + lg * 4) * HID + h * 64 + l15;
#pragma unroll
        for (int dt = 0; dt < 4; dt++)
#pragma unroll
            for (int r = 0; r < 4; r++) {
                union { __bf16 h; ushort u; } cv{(__bf16)(ao[dt][r] * invr[r])};
                ob[(size_t)r * HID + dt * 16] = cv.u;
            }

        // protect LDS buffer reuse across halves (all waves past compute)
        __builtin_amdgcn_s_barrier();
    }
}

// ---------------- launch ----------------
extern "C" void kernel_launch(void* const* d_in, const int* in_sizes, int n_in,
                              void* d_out, int out_size, void* d_ws, size_t ws_size,
                              hipStream_t stream) {
    const float* hidden = (const float*)d_in[0];
    const float* Wq = (const float*)d_in[1];
    const float* Wk = (const float*)d_in[2];
    const float* Wv = (const float*)d_in[3];
    const float* Wo = (const float*)d_in[4];

    char* ws = (char*)d_ws;
    size_t off = 0;
    auto alloc = [&](size_t bytes) -> void* {
        void* p = ws + off;
        off += (bytes + 255) & ~(size_t)255;
        return p;
    };
    ushort* hb   = (ushort*)alloc((size_t)NTOK * HID * 2);
    ushort* wqkv = (ushort*)alloc((size_t)NQKV * 2048 * 2);
    ushort* wo   = (ushort*)alloc((size_t)2048 * 2048 * 2);
    ushort* Qb   = (ushort*)alloc((size_t)NTOK * 2048 * 2);
    ushort* Kb   = (ushort*)alloc((size_t)NTOK * 512 * 2);
    ushort* Vb   = (ushort*)alloc((size_t)NTOK * 512 * 2);
    ushort* Vtb  = (ushort*)alloc((size_t)NTOK * 512 * 2);
    ushort* AO   = (ushort*)alloc((size_t)NTOK * 2048 * 2);

    cvt_all<<<18432, 256, 0, stream>>>(hidden, Wq, Wk, Wv, Wo, hb, wqkv, wo);

    gemm_bt<0, 1><<<dim3(24, 32), 256, 0, stream>>>(hb, wqkv, Qb, Kb, Vb, NTOK, NQKV, 2048);

    transpose_v<<<dim3(S_LEN / 32, 2, BATCH * NKV), 256, 0, stream>>>(Vb, Vtb);

    attn_k<<<dim3(16, BATCH * NH), 256, 0, stream>>>(Qb, Kb, Vtb, AO);

    gemm_bt<1, 0><<<dim3(16, 32), 256, 0, stream>>>(AO, wo, d_out, nullptr, nullptr, NTOK, 2048, 2048);
}

// Round 13
// 169.013 us; speedup vs baseline: 2.5693x; 1.0846x over previous
//
#include <hip/hip_runtime.h>

#define S_LEN 2048
#define BATCH 2
#define NH 32
#define NKV 8
#define HD 64
#define HID 2048
#define NTOK (BATCH * S_LEN)   // 4096
#define NQKV 3072              // 2048 Q + 512 K + 512 V
#define SC_Q 0.18033688011112042f   // 0.125 * log2(e)

typedef __attribute__((ext_vector_type(8))) __bf16 bf16x8;
typedef __attribute__((ext_vector_type(4))) float f32x4;

__device__ inline ushort f2b(float f) {
    union { float f; unsigned u; } x{f};
    unsigned r = (x.u + 0x7fff + ((x.u >> 16) & 1)) >> 16;
    return (ushort)r;
}
__device__ inline float ex2(float x) { return __builtin_amdgcn_exp2f(x); }  // raw v_exp_f32

// ---------------- fused fp32 -> bf16 conversion (all 5 inputs, 1 launch) ----------------
__global__ __launch_bounds__(256) void cvt_all(const float* __restrict__ hidden,
                                               const float* __restrict__ Wq,
                                               const float* __restrict__ Wk,
                                               const float* __restrict__ Wv,
                                               const float* __restrict__ Wo,
                                               ushort* __restrict__ hb,
                                               ushort* __restrict__ wqkv,
                                               ushort* __restrict__ wo) {
    int bid = blockIdx.x;
    const float* src;
    ushort* dst;
    int off;
    if (bid < 8192)        { src = hidden; dst = hb;                              off = bid; }
    else if (bid < 12288)  { src = Wq;     dst = wqkv;                            off = bid - 8192; }
    else if (bid < 13312)  { src = Wk;     dst = wqkv + (size_t)2048 * 2048;      off = bid - 12288; }
    else if (bid < 14336)  { src = Wv;     dst = wqkv + (size_t)2560 * 2048;      off = bid - 13312; }
    else                   { src = Wo;     dst = wo;                              off = bid - 14336; }
    size_t i = (size_t)off * 256 + threadIdx.x;
    float4 v = reinterpret_cast<const float4*>(src)[i];
    ushort4 o;
    o.x = f2b(v.x); o.y = f2b(v.y); o.z = f2b(v.z); o.w = f2b(v.w);
    reinterpret_cast<ushort4*>(dst)[i] = o;
}

// ---------------- global -> LDS async helper ----------------
__device__ inline void gl_lds16(const void* g, void* l) {
    __builtin_amdgcn_global_load_lds((const __attribute__((address_space(1))) void*)g,
                                     (__attribute__((address_space(3))) void*)l, 16, 0, 0);
}

// ---------------- GEMM: C[m][n] = sum_k A[m][k] * B[n][k] ----------------
// BK=64, LDS rows XOR-swizzled via pre-swizzled global source. XCD swizzle.
// ROPE=1: rope+scale Q/K in-register; route head blocks to compact buffers.
template<int WF32, int ROPE>
__global__ __launch_bounds__(256) void gemm_bt(const ushort* __restrict__ A,
                                               const ushort* __restrict__ B,
                                               void* __restrict__ C,
                                               ushort* __restrict__ Kd,
                                               ushort* __restrict__ Vd,
                                               int M, int N, int K) {
    __shared__ __align__(16) ushort As[128 * 64];   // 16 KB
    __shared__ __align__(16) ushort Bs[128 * 64];   // 16 KB
    const int tid = threadIdx.x, lane = tid & 63, w = tid >> 6;
    const int wr = w >> 1, wc = w & 1, l15 = lane & 15, lg = lane >> 4;

    const int nbx = gridDim.x;
    int lid = blockIdx.y * nbx + blockIdx.x;
    const int cpx = (nbx * gridDim.y) >> 3;
    int swz = (lid & 7) * cpx + (lid >> 3);
    const int m0 = (swz / nbx) * 128, n0 = (swz % nbx) * 128;

    const int lsw = ((lane & 7) ^ (lane >> 3)) * 8;   // pre-swizzled source col
    const ushort* Ag = A + (size_t)(m0 + w * 8 + (lane >> 3)) * K + lsw;
    const ushort* Bg = B + (size_t)(n0 + w * 8 + (lane >> 3)) * K + lsw;
    ushort* lA = As + w * 512;
    ushort* lB = Bs + w * 512;

    f32x4 acc[4][4] = {};

    for (int k0 = 0; k0 < K; k0 += 64) {
        __syncthreads();
#pragma unroll
        for (int j = 0; j < 4; j++) {
            gl_lds16(Ag + (size_t)(j * 32) * K + k0, lA + j * 2048);
            gl_lds16(Bg + (size_t)(j * 32) * K + k0, lB + j * 2048);
        }
        __syncthreads();

        const char* pa = (const char*)As + (wr * 64 + l15) * 128;
        const char* pb = (const char*)Bs + (wc * 64 + l15) * 128;
        const int sw = (l15 & 7) * 16;
        bf16x8 af[2][4], bff[2][4];
#pragma unroll
        for (int i = 0; i < 4; i++)
#pragma unroll
            for (int ks = 0; ks < 2; ks++) {
                const int po = (ks * 64 + lg * 16) ^ sw;
                af[ks][i]  = *(const bf16x8*)(pa + i * 2048 + po);
                bff[ks][i] = *(const bf16x8*)(pb + i * 2048 + po);
            }
#pragma unroll
        for (int ks = 0; ks < 2; ks++)
#pragma unroll
            for (int i = 0; i < 4; i++)
#pragma unroll
                for (int j = 0; j < 4; j++)
                    acc[i][j] = __builtin_amdgcn_mfma_f32_16x16x32_bf16(af[ks][i], bff[ks][j], acc[i][j], 0, 0, 0);
    }

    const int mr = m0 + wr * 64 + lg * 4, nc = n0 + wc * 64 + l15;

    if (!ROPE) {
#pragma unroll
        for (int i = 0; i < 4; i++)
#pragma unroll
            for (int j = 0; j < 4; j++)
#pragma unroll
                for (int r = 0; r < 4; r++) {
                    size_t row = mr + i * 16 + r, col = nc + j * 16;
                    if (WF32) ((float*)C)[row * N + col] = acc[i][j][r];
                    else      ((ushort*)C)[row * N + col] = f2b(acc[i][j][r]);
                }
        return;
    }

    // ---- ROPE epilogue: wave-uniform head block (64 cols) ----
    const int hq = (n0 + wc * 64) >> 6;    // 0..31 Q, 32..39 K, 40..47 V
    if (hq < 40) {
        const bool isQ = hq < 32;
        const float fd0 = ex2(-(float)l15 * 0.4152410118609203f);  // 10000^(-l15/32)
        const float fd1 = fd0 * 0.01f;                             // l15+16
#pragma unroll
        for (int i = 0; i < 4; i++)
#pragma unroll
            for (int r = 0; r < 4; r++) {
                float pos = (float)((mr + i * 16 + r) & (S_LEN - 1));
#pragma unroll
                for (int jj = 0; jj < 2; jj++) {
                    float ang = pos * (jj ? fd1 : fd0);
                    float sv, cv;
                    __sincosf(ang, &sv, &cv);
                    float x1 = acc[i][jj][r], x2 = acc[i][jj + 2][r];
                    float y0 = x1 * cv - x2 * sv;
                    float y1 = x2 * cv + x1 * sv;
                    if (isQ) { y0 *= SC_Q; y1 *= SC_Q; }
                    acc[i][jj][r] = y0;
                    acc[i][jj + 2][r] = y1;
                }
            }
    }
    ushort* dst;
    int dstride, colb;
    if (hq < 32)      { dst = (ushort*)C; dstride = 2048; colb = nc; }
    else if (hq < 40) { dst = Kd;         dstride = 512;  colb = nc - 2048; }
    else              { dst = Vd;         dstride = 512;  colb = nc - 2560; }
#pragma unroll
    for (int i = 0; i < 4; i++)
#pragma unroll
        for (int j = 0; j < 4; j++)
#pragma unroll
            for (int r = 0; r < 4; r++) {
                size_t row = mr + i * 16 + r;
                dst[row * dstride + colb + j * 16] = f2b(acc[i][j][r]);
            }
}

// ---------------- V transpose: Vb [NTOK][512] -> Vt [b][kvh][64][S] ----------------
__global__ __launch_bounds__(256) void transpose_v(const ushort* __restrict__ V,
                                                   ushort* __restrict__ Vt) {
    __shared__ ushort tile[32][33];
    int bz = blockIdx.z, b = bz >> 3, kvh = bz & 7;
    int s0 = blockIdx.x * 32, d0 = blockIdx.y * 32;
    int tx = threadIdx.x & 31, ty = threadIdx.x >> 5;
#pragma unroll
    for (int i = 0; i < 4; i++)
        tile[ty + i * 8][tx] = V[(size_t)(b * S_LEN + s0 + ty + i * 8) * 512 + kvh * 64 + d0 + tx];
    __syncthreads();
#pragma unroll
    for (int i = 0; i < 4; i++)
        Vt[((size_t)((b * 8 + kvh) * 64 + d0 + ty + i * 8)) * S_LEN + s0 + tx] = tile[tx][ty + i * 8];
}

// ---------------- Flash attention (causal, GQA) ----------------
// 2 q-subtiles per wave (q0, q0+64) against the SAME staged K/V tile:
// halves LDS bytes per MFMA and barriers per unit work. Block = 128 q rows.
// Grid 512 blocks = exactly 2/CU fully resident, uniform 34 iters (pair p,15-p).
// 3-buffer counted-vmcnt pipeline; no online max; row sums via MFMA-ones.
__global__ __launch_bounds__(256) void attn_k(const ushort* __restrict__ Q,   // stride 2048
                                              const ushort* __restrict__ Kc,  // stride 512
                                              const ushort* __restrict__ Vt,
                                              ushort* __restrict__ O) {
    __shared__ __align__(16) ushort K_lds[3][4096];   // 24 KB
    __shared__ __align__(16) ushort V_lds[3][4096];   // 24 KB
    const int lane = threadIdx.x & 63, w = threadIdx.x >> 6;
    const int l15 = lane & 15, lg = lane >> 4;

    // grid (8, 64): 512 blocks; XCD swizzle (512 % 8 == 0)
    int lid = blockIdx.y * 8 + blockIdx.x;
    int swz = (lid & 7) * 64 + (lid >> 3);
    const int ps = swz & 7;
    const int bh = swz >> 3;
    const int b = bh >> 5, h = bh & 31, kvh = h >> 2;

    const ushort* kSrc[2];
    const ushort* vSrc[2];
    int dstU[2];
#pragma unroll
    for (int j = 0; j < 2; j++) {
        int u = w * 2 + j;
        int row = u * 8 + (lane >> 3);
        int po = (lane & 7) * 16;
        int fr = ((row & 3) | (((row >> 3) & 1) << 2)) << 4;
        int dus = (po ^ fr) >> 1;
        kSrc[j] = Kc + (size_t)(b * S_LEN + row) * 512 + kvh * 64 + dus;
        vSrc[j] = Vt + ((size_t)((b * 8 + kvh) * 64 + row)) * S_LEN + dus;
        dstU[j] = u * 512;
    }

    int fr_k = ((l15 & 3) | (((l15 >> 2) & 1) << 2)) << 4;
    int kbase = 1024 * (l15 >> 2) + 128 * (l15 & 3) + ((lg * 16) ^ (fr_k & 48));
    int k6 = (fr_k >> 6) & 1;
    int kb0 = kbase + 64 * k6, kb1 = kbase + 64 * (1 - k6);
    int fr_v = ((l15 & 3) | (((l15 >> 3) & 1) << 2)) << 4;
    int vbase = 128 * l15 + ((lg * 16) ^ (fr_v & 48));
    int v6 = (fr_v >> 6) & 1;
    int vb0 = vbase + 64 * v6, vb1 = vbase + 64 * (1 - v6);

    bf16x8 onesf;
#pragma unroll
    for (int i = 0; i < 8; i++) onesf[i] = (__bf16)1.0f;

    for (int half = 0; half < 2; ++half) {
        const int pp = half ? (15 - ps) : ps;         // 128-row q-block index
        const int q0A = pp * 128 + w * 16, q0B = q0A + 64;
        const int qrowA = q0A + l15, qrowB = q0B + l15;
        const int ktA = 2 * pp, ktB = 2 * pp + 1;     // last kv tiles for A / B

        const ushort* qpA = Q + (size_t)(b * S_LEN + qrowA) * HID + h * 64 + lg * 8;
        const ushort* qpB = Q + (size_t)(b * S_LEN + qrowB) * HID + h * 64 + lg * 8;
        bf16x8 qfA0 = *(const bf16x8*)qpA, qfA1 = *(const bf16x8*)(qpA + 32);
        bf16x8 qfB0 = *(const bf16x8*)qpB, qfB1 = *(const bf16x8*)(qpB + 32);
        // drain Q loads (and prior O-stores) so in-loop vmcnt tracks staging only
        asm volatile("s_waitcnt vmcnt(0)" ::: "memory");

        f32x4 aoA[4] = {}, aoB[4] = {};
        f32x4 lsumA = {}, lsumB = {};

        // 3-buffer pipeline: stage tiles 0 and 1 (ktB >= 1 always)
        int i0 = 0, i1 = 1, i2 = 2;
#pragma unroll
        for (int j = 0; j < 2; j++) {
            gl_lds16(kSrc[j], &K_lds[0][dstU[j]]);
            gl_lds16(vSrc[j], &V_lds[0][dstU[j]]);
        }
#pragma unroll
        for (int j = 0; j < 2; j++) {
            gl_lds16(kSrc[j] + (size_t)64 * 512, &K_lds[1][dstU[j]]);
            gl_lds16(vSrc[j] + 64, &V_lds[1][dstU[j]]);
        }

        for (int kt = 0; kt <= ktB; ++kt) {
            const int kn = kt << 6;
            if (kt < ktB) asm volatile("s_waitcnt vmcnt(4)" ::: "memory");
            else          asm volatile("s_waitcnt vmcnt(0)" ::: "memory");
            __builtin_amdgcn_s_barrier();

            if (kt + 2 <= ktB) {
                const int kn2 = kn + 128;
#pragma unroll
                for (int j = 0; j < 2; j++) {
                    gl_lds16(kSrc[j] + (size_t)kn2 * 512, &K_lds[i2][dstU[j]]);
                    gl_lds16(vSrc[j] + kn2, &V_lds[i2][dstU[j]]);
                }
            }

            const char* Kt = (const char*)&K_lds[i0][0];
            const char* Vl = (const char*)&V_lds[i0][0];
            const bool aAct = (kt <= ktA);

            bf16x8 kf0[4], kf1[4];
#pragma unroll
            for (int kc = 0; kc < 4; kc++) {
                const int kcst = 4096 * (kc >> 1) + 512 * (kc & 1);
                kf0[kc] = *(const bf16x8*)(Kt + kb0 + kcst);
                kf1[kc] = *(const bf16x8*)(Kt + kb1 + kcst);
            }

            // ---- QK^T for B (always) and A (while active) ----
            f32x4 sB[4], sA[4];
#pragma unroll
            for (int kc = 0; kc < 4; kc++) {
                f32x4 z = {};
                z = __builtin_amdgcn_mfma_f32_16x16x32_bf16(kf0[kc], qfB0, z, 0, 0, 0);
                z = __builtin_amdgcn_mfma_f32_16x16x32_bf16(kf1[kc], qfB1, z, 0, 0, 0);
                sB[kc] = z;
            }
            if (aAct) {
#pragma unroll
                for (int kc = 0; kc < 4; kc++) {
                    f32x4 z = {};
                    z = __builtin_amdgcn_mfma_f32_16x16x32_bf16(kf0[kc], qfA0, z, 0, 0, 0);
                    z = __builtin_amdgcn_mfma_f32_16x16x32_bf16(kf1[kc], qfA1, z, 0, 0, 0);
                    sA[kc] = z;
                }
            }

            // ---- diagonal masks ----
            if (kt == ktB) {
#pragma unroll
                for (int kc = 0; kc < 4; kc++)
#pragma unroll
                    for (int r = 0; r < 4; r++) {
                        int kv = kn + ((kc >> 1) << 5) + (lg << 3) + ((kc & 1) << 2) + r;
                        sB[kc][r] = (kv <= qrowB) ? sB[kc][r] : -INFINITY;
                    }
            }
            if (kt == ktA) {
#pragma unroll
                for (int kc = 0; kc < 4; kc++)
#pragma unroll
                    for (int r = 0; r < 4; r++) {
                        int kv = kn + ((kc >> 1) << 5) + (lg << 3) + ((kc & 1) << 2) + r;
                        sA[kc][r] = (kv <= qrowA) ? sA[kc][r] : -INFINITY;
                    }
            }

            // ---- p = exp2(s), pack, row-sum MFMA, PV ----
            bf16x8 pB0, pB1, pA0, pA1;
#pragma unroll
            for (int r = 0; r < 4; r++) {
                pB0[r]     = (__bf16)ex2(sB[0][r]);
                pB0[4 + r] = (__bf16)ex2(sB[1][r]);
                pB1[r]     = (__bf16)ex2(sB[2][r]);
                pB1[4 + r] = (__bf16)ex2(sB[3][r]);
            }
            if (aAct) {
#pragma unroll
                for (int r = 0; r < 4; r++) {
                    pA0[r]     = (__bf16)ex2(sA[0][r]);
                    pA0[4 + r] = (__bf16)ex2(sA[1][r]);
                    pA1[r]     = (__bf16)ex2(sA[2][r]);
                    pA1[4 + r] = (__bf16)ex2(sA[3][r]);
                }
            }

            lsumB = __builtin_amdgcn_mfma_f32_16x16x32_bf16(pB0, onesf, lsumB, 0, 0, 0);
            lsumB = __builtin_amdgcn_mfma_f32_16x16x32_bf16(pB1, onesf, lsumB, 0, 0, 0);
            if (aAct) {
                lsumA = __builtin_amdgcn_mfma_f32_16x16x32_bf16(pA0, onesf, lsumA, 0, 0, 0);
                lsumA = __builtin_amdgcn_mfma_f32_16x16x32_bf16(pA1, onesf, lsumA, 0, 0, 0);
            }

#pragma unroll
            for (int dt = 0; dt < 4; dt++) {
                bf16x8 vf0 = *(const bf16x8*)(Vl + vb0 + dt * 2048);
                bf16x8 vf1 = *(const bf16x8*)(Vl + vb1 + dt * 2048);
                aoB[dt] = __builtin_amdgcn_mfma_f32_16x16x32_bf16(pB0, vf0, aoB[dt], 0, 0, 0);
                aoB[dt] = __builtin_amdgcn_mfma_f32_16x16x32_bf16(pB1, vf1, aoB[dt], 0, 0, 0);
                if (aAct) {
                    aoA[dt] = __builtin_amdgcn_mfma_f32_16x16x32_bf16(pA0, vf0, aoA[dt], 0, 0, 0);
                    aoA[dt] = __builtin_amdgcn_mfma_f32_16x16x32_bf16(pA1, vf1, aoA[dt], 0, 0, 0);
                }
            }

            int t = i0; i0 = i1; i1 = i2; i2 = t;   // rotate buffers
        }

        // ---- epilogue: both subtiles ----
        float invA[4], invB[4];
#pragma unroll
        for (int r = 0; r < 4; r++) { invA[r] = 1.0f / lsumA[r]; invB[r] = 1.0f / lsumB[r]; }
        ushort* obA = O + (size_t)(b * S_LEN + q0A + lg * 4) * HID + h * 64 + l15;
        ushort* obB = O + (size_t)(b * S_LEN + q0B + lg * 4) * HID + h * 64 + l15;
#pragma unroll
        for (int dt = 0; dt < 4; dt++)
#pragma unroll
            for (int r = 0; r < 4; r++) {
                union { __bf16 h; ushort u; } cA{(__bf16)(aoA[dt][r] * invA[r])};
                union { __bf16 h; ushort u; } cB{(__bf16)(aoB[dt][r] * invB[r])};
                obA[(size_t)r * HID + dt * 16] = cA.u;
                obB[(size_t)r * HID + dt * 16] = cB.u;
            }

        // protect LDS buffer reuse across halves
        __builtin_amdgcn_s_barrier();
    }
}

// ---------------- launch ----------------
extern "C" void kernel_launch(void* const* d_in, const int* in_sizes, int n_in,
                              void* d_out, int out_size, void* d_ws, size_t ws_size,
                              hipStream_t stream) {
    const float* hidden = (const float*)d_in[0];
    const float* Wq = (const float*)d_in[1];
    const float* Wk = (const float*)d_in[2];
    const float* Wv = (const float*)d_in[3];
    const float* Wo = (const float*)d_in[4];

    char* ws = (char*)d_ws;
    size_t off = 0;
    auto alloc = [&](size_t bytes) -> void* {
        void* p = ws + off;
        off += (bytes + 255) & ~(size_t)255;
        return p;
    };
    ushort* hb   = (ushort*)alloc((size_t)NTOK * HID * 2);
    ushort* wqkv = (ushort*)alloc((size_t)NQKV * 2048 * 2);
    ushort* wo   = (ushort*)alloc((size_t)2048 * 2048 * 2);
    ushort* Qb   = (ushort*)alloc((size_t)NTOK * 2048 * 2);
    ushort* Kb   = (ushort*)alloc((size_t)NTOK * 512 * 2);
    ushort* Vb   = (ushort*)alloc((size_t)NTOK * 512 * 2);
    ushort* Vtb  = (ushort*)alloc((size_t)NTOK * 512 * 2);
    ushort* AO   = (ushort*)alloc((size_t)NTOK * 2048 * 2);

    cvt_all<<<18432, 256, 0, stream>>>(hidden, Wq, Wk, Wv, Wo, hb, wqkv, wo);

    gemm_bt<0, 1><<<dim3(24, 32), 256, 0, stream>>>(hb, wqkv, Qb, Kb, Vb, NTOK, NQKV, 2048);

    transpose_v<<<dim3(S_LEN / 32, 2, BATCH * NKV), 256, 0, stream>>>(Vb, Vtb);

    attn_k<<<dim3(8, BATCH * NH), 256, 0, stream>>>(Qb, Kb, Vtb, AO);

    gemm_bt<1, 0><<<dim3(16, 32), 256, 0, stream>>>(AO, wo, d_out, nullptr, nullptr, NTOK, 2048, 2048);
}